// Round 9
// baseline (1676.577 us; speedup 1.0000x reference)
//
#include <hip/hip_runtime.h>

// PathDecoder: B=256, L=192, H=320, E=128, V=27000, T=8
constexpr int Bn = 256;
constexpr int Ln = 192;
constexpr int Hn = 320;
constexpr int En = 128;
constexpr int Vn = 27000;
constexpr int Tn = 8;
constexpr float NEGV   = -1e9f;
constexpr float LN_EPS = 1e-5f;
constexpr int G  = 256;   // workgroups (<=256 CUs -> co-resident)
constexpr int BT = 512;   // 8 waves

typedef __attribute__((ext_vector_type(8))) short bf16x8;
typedef __attribute__((ext_vector_type(4))) float f32x4;
typedef unsigned long long u64;
typedef unsigned int u32;
typedef unsigned short u16;

__device__ __forceinline__ float sigmoidf_(float x) { return 1.f / (1.f + expf(-x)); }
__device__ __forceinline__ u16 f2bf(float x) {
  unsigned u = __float_as_uint(x);
  return (u16)((u + 0x7fffu + ((u >> 16) & 1u)) >> 16);
}
__device__ __forceinline__ float bf2f(u16 h) { return __uint_as_float((unsigned)h << 16); }
__device__ __forceinline__ unsigned mono(float f) {
  unsigned u = __float_as_uint(f);
  return (u & 0x80000000u) ? ~u : (u | 0x80000000u);
}
__device__ __forceinline__ u64 shfl_xor_u64(u64 x, int off) {
  unsigned lo = (unsigned)x, hi = (unsigned)(x >> 32);
  lo = __shfl_xor(lo, off, 64);
  hi = __shfl_xor(hi, off, 64);
  return ((u64)hi << 32) | lo;
}

#define AT_LD(p)    __hip_atomic_load((p), __ATOMIC_RELAXED, __HIP_MEMORY_SCOPE_AGENT)
#define AT_ST(p, v) __hip_atomic_store((p), (v), __ATOMIC_RELAXED, __HIP_MEMORY_SCOPE_AGENT)

template <int SLP>
__device__ __forceinline__ void spin(unsigned* p, unsigned e) {
  while (__hip_atomic_load(p, __ATOMIC_RELAXED, __HIP_MEMORY_SCOPE_AGENT) < e)
    __builtin_amdgcn_s_sleep(SLP);
}

// Two-level tree grid barrier.
// HEAVY: release/acquire (wbl2/invl2) — used ONCE after prep.
// light: relaxed flags only — cross-block step data travels via agent-relaxed
//        atomics (LLC-coherent, L2-bypassing), so no cache maintenance needed.
template <bool HEAVY>
__device__ void gridbar(unsigned* flags, unsigned* xdone, unsigned* go, unsigned e) {
  __syncthreads();   // compiler drains vmcnt before s_barrier -> stores complete
  const int bid = blockIdx.x, tid = threadIdx.x;
  if (bid >= 8) {
    if (tid == 0) {
      if (HEAVY) __hip_atomic_store(&flags[bid * 32], e, __ATOMIC_RELEASE, __HIP_MEMORY_SCOPE_AGENT);
      else       AT_ST(&flags[bid * 32], e);
      spin<8>(&go[(bid & 7) * 32], e);
      if (HEAVY) {
        unsigned v = __hip_atomic_load(&go[(bid & 7) * 32], __ATOMIC_ACQUIRE, __HIP_MEMORY_SCOPE_AGENT);
        asm volatile("" :: "v"(v));
      }
    }
    __syncthreads();
  } else if (bid != 0) {
    if (tid >= 1 && tid < 32) spin<4>(&flags[(bid + tid * 8) * 32], e);
    __syncthreads();
    if (tid == 0) {
      if (HEAVY) __hip_atomic_store(&xdone[bid * 32], e, __ATOMIC_RELEASE, __HIP_MEMORY_SCOPE_AGENT);
      else       AT_ST(&xdone[bid * 32], e);
      spin<8>(&go[bid * 32], e);
      if (HEAVY) {
        unsigned v = __hip_atomic_load(&go[bid * 32], __ATOMIC_ACQUIRE, __HIP_MEMORY_SCOPE_AGENT);
        asm volatile("" :: "v"(v));
      }
    }
    __syncthreads();
  } else {
    if (tid >= 1 && tid < 32) spin<4>(&flags[(tid * 8) * 32], e);
    if (tid >= 32 && tid < 39) spin<4>(&xdone[(tid - 31) * 32], e);
    __syncthreads();
    if (tid < 8) {
      if (HEAVY) {
        unsigned v = __hip_atomic_load(&xdone[((tid == 0) ? 1 : tid) * 32],
                                       __ATOMIC_ACQUIRE, __HIP_MEMORY_SCOPE_AGENT);
        asm volatile("" :: "v"(v));
        __hip_atomic_store(&go[tid * 32], e, __ATOMIC_RELEASE, __HIP_MEMORY_SCOPE_AGENT);
      } else {
        AT_ST(&go[tid * 32], e);
      }
    }
    __syncthreads();
  }
}

__global__ __launch_bounds__(1024) void k_zero(unsigned* flags, int n) {
  for (int i = blockIdx.x * 1024 + threadIdx.x; i < n; i += gridDim.x * 1024) flags[i] = 0u;
}

// ---------------------------------------------------------------------------
__global__ __launch_bounds__(BT, 2) void k_all(
    const float* __restrict__ enc, const int* __restrict__ lens,
    const float* __restrict__ emb,
    const float* __restrict__ w_ih, const float* __restrict__ w_hh,
    const float* __restrict__ b_ih, const float* __restrict__ b_hh,
    const float* __restrict__ attn_w, const float* __restrict__ concat_w,
    const float* __restrict__ gamma, const float* __restrict__ beta,
    const float* __restrict__ proj_w, float* __restrict__ out,
    unsigned* flags, unsigned* xdone, unsigned* go,
    float* h32, float* c32, float* awT, float* cwT, float* biasc,
    u64* amax, u32* hhl, u32* thl,
    u16* wch, u16* wcl, u16* ebh, u16* ebl, u16* pwh, u16* pwl) {
  __shared__ float eL[64 * Hn];        // 80 KB: enc chunk (B) / A-panel hi+lo (C)
  __shared__ float hs[Hn], ahs[Hn], cts[Hn];
  __shared__ float sc[64];
  __shared__ float rmS, rsS, rfS, rmu, rvar;

  const int bid = blockIdx.x, tid = threadIdx.x;
  const int wv = tid >> 6, lane = tid & 63;
  const int gid = bid * BT + tid;
  const int NT = G * BT;
  const size_t HB = (size_t)Bn * Hn;
  unsigned nb = 0;

  // ================= phase 0: one-time prep (normal stores; heavy barrier) ===
  for (int i = gid; i < Vn * Hn / 4; i += NT) {
    float4 v = ((const float4*)proj_w)[i];
    u16 h0_ = f2bf(v.x), h1_ = f2bf(v.y), h2_ = f2bf(v.z), h3_ = f2bf(v.w);
    ((ushort4*)pwh)[i] = make_ushort4(h0_, h1_, h2_, h3_);
    ((ushort4*)pwl)[i] = make_ushort4(f2bf(v.x - bf2f(h0_)), f2bf(v.y - bf2f(h1_)),
                                      f2bf(v.z - bf2f(h2_)), f2bf(v.w - bf2f(h3_)));
  }
  for (int i = gid; i < Vn * En / 4; i += NT) {
    float4 v = ((const float4*)emb)[i];
    u16 h0_ = f2bf(v.x), h1_ = f2bf(v.y), h2_ = f2bf(v.z), h3_ = f2bf(v.w);
    ((ushort4*)ebh)[i] = make_ushort4(h0_, h1_, h2_, h3_);
    ((ushort4*)ebl)[i] = make_ushort4(f2bf(v.x - bf2f(h0_)), f2bf(v.y - bf2f(h1_)),
                                      f2bf(v.z - bf2f(h2_)), f2bf(v.w - bf2f(h3_)));
  }
  for (int i = gid; i < 4 * Hn * 112; i += NT) {  // w_cat [1280][448] split
    int r = i / 112, k = (i % 112) * 4;
    const float* src = (k < En) ? (w_ih + (size_t)r * En + k)
                                : (w_hh + (size_t)r * Hn + (k - En));
    float4 v = *(const float4*)src;
    size_t o = (size_t)r * 448 + k;
    u16 h0_ = f2bf(v.x), h1_ = f2bf(v.y), h2_ = f2bf(v.z), h3_ = f2bf(v.w);
    *(ushort4*)(wch + o) = make_ushort4(h0_, h1_, h2_, h3_);
    *(ushort4*)(wcl + o) = make_ushort4(f2bf(v.x - bf2f(h0_)), f2bf(v.y - bf2f(h1_)),
                                        f2bf(v.z - bf2f(h2_)), f2bf(v.w - bf2f(h3_)));
  }
  for (int i = gid; i < Hn * Hn; i += NT) {       // awT[k][j] = attn_w[j][k]
    int k = i / Hn, j = i % Hn;
    awT[i] = attn_w[(size_t)j * Hn + k];
  }
  for (int i = gid; i < 2 * Hn * Hn; i += NT) {   // cwT[k][j] = concat_w[j][k]
    int k = i / Hn, j = i % Hn;
    cwT[i] = concat_w[(size_t)j * (2 * Hn) + k];
  }
  for (int i = gid; i < 4 * Hn; i += NT) biasc[i] = b_ih[i] + b_hh[i];
  for (int i = gid; i < Tn * Bn; i += NT) amax[i] = 0ull;
  {
    if (tid < Hn) {
      const float* p = enc + (size_t)bid * Ln * Hn + tid;
      float s = 0.f;
#pragma unroll 4
      for (int l = 0; l < Ln; ++l) s += p[(size_t)l * Hn];
      float hv = s / (float)lens[bid];
      size_t o = (size_t)bid * Hn + tid;
      h32[o] = hv; c32[o] = hv;
      u16 hb = f2bf(hv), lb = f2bf(hv - bf2f(hb));
      hhl[o] = (u32)hb | ((u32)lb << 16);
    }
  }
  nb += 1; gridbar<true>(flags, xdone, go, nb);   // ONE heavy barrier

  // ================= decode steps =================
  for (int t = 0; t < Tn; ++t) {
    const int hin = t & 1, hout = hin ^ 1;

    // ---- phase A: gates GEMM (split-bf16 MFMA) + LSTM cell ----
    // 20 blocks x 8 waves; wave tile = 32 b-rows x (4 gates x 16 h-cols)
    if (bid < 20) {
      int j0 = bid * 16;
      int b0 = wv * 32;
      int lr = lane & 15, hi4 = lane >> 4, kg = hi4 * 8;
      int tkr[2];
#pragma unroll
      for (int mt = 0; mt < 2; ++mt) {
        int r = b0 + mt * 16 + lr;
        if (t == 0) tkr[mt] = 1;
        else {
          u64 a = AT_LD(&amax[(size_t)(t - 1) * Bn + r]);
          tkr[mt] = (int)(~(unsigned)a);
        }
      }
      f32x4 acc[2][4];
#pragma unroll
      for (int i = 0; i < 2; ++i)
#pragma unroll
        for (int j = 0; j < 4; ++j) acc[i][j] = (f32x4){0.f, 0.f, 0.f, 0.f};
      const u32* hin_p = hhl + (size_t)hin * HB;
      for (int k0 = 0; k0 < 448; k0 += 32) {
        bf16x8 af[2][2], bw[4][2];
#pragma unroll
        for (int mt = 0; mt < 2; ++mt) {
          int r = b0 + mt * 16 + lr;
          if (k0 < En) {
            size_t o = (size_t)tkr[mt] * En + k0 + kg;
            af[mt][0] = *(const bf16x8*)(ebh + o);
            af[mt][1] = *(const bf16x8*)(ebl + o);
          } else {
            size_t o = (size_t)r * Hn + (k0 - En) + kg;
            u32 w[8];
#pragma unroll
            for (int q = 0; q < 8; ++q) w[q] = AT_LD((u32*)&hin_p[o + q]);
#pragma unroll
            for (int q = 0; q < 8; ++q) {
              af[mt][0][q] = (short)(w[q] & 0xffffu);
              af[mt][1][q] = (short)(w[q] >> 16);
            }
          }
        }
#pragma unroll
        for (int g = 0; g < 4; ++g) {
          size_t o = (size_t)(g * Hn + j0 + lr) * 448 + k0 + kg;
          bw[g][0] = *(const bf16x8*)(wch + o);
          bw[g][1] = *(const bf16x8*)(wcl + o);
        }
#pragma unroll
        for (int mt = 0; mt < 2; ++mt)
#pragma unroll
          for (int g = 0; g < 4; ++g) {
            acc[mt][g] = __builtin_amdgcn_mfma_f32_16x16x32_bf16(af[mt][0], bw[g][0], acc[mt][g], 0, 0, 0);
            acc[mt][g] = __builtin_amdgcn_mfma_f32_16x16x32_bf16(af[mt][0], bw[g][1], acc[mt][g], 0, 0, 0);
            acc[mt][g] = __builtin_amdgcn_mfma_f32_16x16x32_bf16(af[mt][1], bw[g][0], acc[mt][g], 0, 0, 0);
          }
      }
      int jc = j0 + lr;
      const float* c_i = c32 + (size_t)hin * HB;   // block-local: normal, L2-hot
      float* c_o = c32 + (size_t)hout * HB;
#pragma unroll
      for (int mt = 0; mt < 2; ++mt)
#pragma unroll
        for (int j = 0; j < 4; ++j) {
          int b = b0 + mt * 16 + hi4 * 4 + j;
          float iv = acc[mt][0][j] + biasc[jc];
          float fv = acc[mt][1][j] + biasc[Hn + jc];
          float gv = acc[mt][2][j] + biasc[2 * Hn + jc];
          float ov = acc[mt][3][j] + biasc[3 * Hn + jc];
          float co = c_i[(size_t)b * Hn + jc];
          float cn = sigmoidf_(fv) * co + sigmoidf_(iv) * tanhf(gv);
          float hn = sigmoidf_(ov) * tanhf(cn);
          size_t o = (size_t)b * Hn + jc;
          c_o[o] = cn;
          AT_ST(&h32[(size_t)hout * HB + o], hn);
          u16 hb = f2bf(hn), lb = f2bf(hn - bf2f(hb));
          AT_ST(&hhl[(size_t)hout * HB + o], (u32)hb | ((u32)lb << 16));
        }
    }
    nb += 1; gridbar<false>(flags, xdone, go, nb);

    // ---- phase B: attention (online softmax, single enc pass) + cat + LN ----
    {
      int b = bid;
      if (tid < Hn) hs[tid] = AT_LD(&h32[(size_t)hout * HB + (size_t)b * Hn + tid]);
      __syncthreads();
      if (tid < Hn) {
        float s = 0.f;
#pragma unroll 8
        for (int k = 0; k < Hn; ++k) s += awT[(size_t)k * Hn + tid] * hs[k];
        ahs[tid] = s;
      }
      if (tid == 0) { rmS = -3.402823466e38f; rsS = 0.f; }
      __syncthreads();

      int len = lens[b];
      float ctxacc = 0.f;
      const float* encB = enc + (size_t)b * Ln * Hn;
      for (int c = 0; c < 3; ++c) {
        const float4* src = (const float4*)(encB + (size_t)c * 64 * Hn);
#pragma unroll
        for (int i = 0; i < 10; ++i) ((float4*)eL)[tid + i * BT] = src[tid + i * BT];
        __syncthreads();
#pragma unroll
        for (int r = 0; r < 8; ++r) {
          int l = wv * 8 + r;
          float s = 0.f;
#pragma unroll
          for (int c5 = 0; c5 < 5; ++c5)
            s += eL[l * Hn + lane + 64 * c5] * ahs[lane + 64 * c5];
#pragma unroll
          for (int off = 32; off > 0; off >>= 1) s += __shfl_xor(s, off, 64);
          if (lane == 0) sc[l] = s + ((c * 64 + l < len) ? 0.f : NEGV);
        }
        __syncthreads();
        if (wv == 0) {
          float v = sc[lane];
          float m = v;
#pragma unroll
          for (int off = 32; off > 0; off >>= 1) m = fmaxf(m, __shfl_xor(m, off, 64));
          float oldm = rmS;
          float newm = fmaxf(oldm, m);
          float p = expf(v - newm);
          sc[lane] = p;
          float s = p;
#pragma unroll
          for (int off = 32; off > 0; off >>= 1) s += __shfl_xor(s, off, 64);
          if (lane == 0) {
            float f = expf(oldm - newm);
            rfS = f;
            rsS = rsS * f + s;
            rmS = newm;
          }
        }
        __syncthreads();
        if (tid < Hn) {
          float f = rfS;
          float a = 0.f;
#pragma unroll 8
          for (int l = 0; l < 64; ++l) a += sc[l] * eL[l * Hn + tid];
          ctxacc = ctxacc * f + a;
        }
        __syncthreads();
      }
      if (tid < Hn) cts[tid] = ctxacc / rsS;
      __syncthreads();

      float catv = 0.f;
      if (tid < Hn) {
        float s = 0.f;
#pragma unroll 8
        for (int k = 0; k < Hn; ++k) s += cwT[(size_t)k * Hn + tid] * hs[k];
#pragma unroll 8
        for (int k = 0; k < Hn; ++k) s += cwT[(size_t)(Hn + k) * Hn + tid] * cts[k];
        catv = s;
        ahs[tid] = s;
      }
      __syncthreads();
      if (tid < 64) {
        float s1 = 0.f, s2 = 0.f;
        for (int i = tid; i < Hn; i += 64) { float v = ahs[i]; s1 += v; s2 += v * v; }
#pragma unroll
        for (int off = 32; off > 0; off >>= 1) {
          s1 += __shfl_xor(s1, off, 64);
          s2 += __shfl_xor(s2, off, 64);
        }
        if (tid == 0) {
          float mu = s1 * (1.f / 320.f);
          rmu = mu;
          rvar = s2 * (1.f / 320.f) - mu * mu;
        }
      }
      __syncthreads();
      if (tid < Hn) {
        float rstd = 1.f / sqrtf(rvar + LN_EPS);
        float y = (catv - rmu) * rstd * gamma[tid] + beta[tid];
        float tv = tanhf(y);
        u16 tb = f2bf(tv), lb = f2bf(tv - bf2f(tb));
        AT_ST(&thl[(size_t)b * Hn + tid], (u32)tb | ((u32)lb << 16));
      }
    }
    nb += 1; gridbar<false>(flags, xdone, go, nb);

    // ---- phase C: projection (split-bf16 MFMA) + fused argmax ----
    // Block mapping: xcd = bid&7, s = bid>>3, mb = s&3 (shared by all 8 waves),
    // g = s>>2; wave's vb = xcd*53 + g*8 + wv (53 panels/xcd, 51 for xcd 7).
    {
      const int xcd = bid & 7, s_ = bid >> 3;
      const int mb = s_ & 3, g = s_ >> 2;
      const int nvb = (xcd == 7) ? 51 : 53;
      const int rows0 = mb * 64;
      u16* Ahi = (u16*)eL;
      u16* Alo = Ahi + 64 * Hn;

      // stage A-panel (64 rows of thl) into LDS, split hi/lo, XOR-swizzled
      for (int i = tid; i < 64 * Hn / 4; i += BT) {
        int r = i / (Hn / 4);
        int k = (i % (Hn / 4)) * 4;
        u32 w0 = AT_LD(&thl[(size_t)(rows0 + r) * Hn + k + 0]);
        u32 w1 = AT_LD(&thl[(size_t)(rows0 + r) * Hn + k + 1]);
        u32 w2 = AT_LD(&thl[(size_t)(rows0 + r) * Hn + k + 2]);
        u32 w3 = AT_LD(&thl[(size_t)(rows0 + r) * Hn + k + 3]);
        int off = ((r * Hn + k) * 2) ^ ((r & 7) << 4);
        *(ushort4*)((char*)Ahi + off) =
            make_ushort4((u16)w0, (u16)w1, (u16)w2, (u16)w3);
        *(ushort4*)((char*)Alo + off) =
            make_ushort4((u16)(w0 >> 16), (u16)(w1 >> 16), (u16)(w2 >> 16), (u16)(w3 >> 16));
      }
      __syncthreads();

      int idx = g * 8 + wv;
      if (idx < nvb) {
        int vb = xcd * 53 + idx;
        int v0 = vb * 64;
        int lr = lane & 15, hi4 = lane >> 4, kg = hi4 * 8;
        f32x4 acc[4][4];
#pragma unroll
        for (int i = 0; i < 4; ++i)
#pragma unroll
          for (int j = 0; j < 4; ++j) acc[i][j] = (f32x4){0.f, 0.f, 0.f, 0.f};
        const bf16x8 zf = {0, 0, 0, 0, 0, 0, 0, 0};
        for (int k0 = 0; k0 < Hn; k0 += 32) {
          bf16x8 af[4][2], bw[4][2];
#pragma unroll
          for (int mt = 0; mt < 4; ++mt) {
            int rr = mt * 16 + lr;
            int off = ((rr * Hn + k0 + kg) * 2) ^ ((rr & 7) << 4);
            af[mt][0] = *(const bf16x8*)((char*)Ahi + off);
            af[mt][1] = *(const bf16x8*)((char*)Alo + off);
          }
#pragma unroll
          for (int nt = 0; nt < 4; ++nt) {
            int v = v0 + nt * 16 + lr;
            if (v < Vn) {
              size_t o = (size_t)v * Hn + k0 + kg;
              bw[nt][0] = *(const bf16x8*)(pwh + o);
              bw[nt][1] = *(const bf16x8*)(pwl + o);
            } else {
              bw[nt][0] = zf; bw[nt][1] = zf;
            }
          }
#pragma unroll
          for (int mt = 0; mt < 4; ++mt)
#pragma unroll
            for (int nt = 0; nt < 4; ++nt) {
              acc[mt][nt] = __builtin_amdgcn_mfma_f32_16x16x32_bf16(af[mt][0], bw[nt][0], acc[mt][nt], 0, 0, 0);
              acc[mt][nt] = __builtin_amdgcn_mfma_f32_16x16x32_bf16(af[mt][0], bw[nt][1], acc[mt][nt], 0, 0, 0);
              acc[mt][nt] = __builtin_amdgcn_mfma_f32_16x16x32_bf16(af[mt][1], bw[nt][0], acc[mt][nt], 0, 0, 0);
            }
        }
        float* ot = out + (size_t)t * Bn * Vn;
#pragma unroll
        for (int mt = 0; mt < 4; ++mt)
#pragma unroll
          for (int nt = 0; nt < 4; ++nt) {
            int v = v0 + nt * 16 + lr;
            if (v < Vn) {
#pragma unroll
              for (int j = 0; j < 4; ++j)
                __builtin_nontemporal_store(acc[mt][nt][j],
                    &ot[(size_t)(rows0 + mt * 16 + hi4 * 4 + j) * Vn + v]);
            }
          }
        // argmax: key = (mono(val)<<32) | ~idx ; max key == first max
#pragma unroll
        for (int mt = 0; mt < 4; ++mt)
#pragma unroll
          for (int j = 0; j < 4; ++j) {
            u64 k = 0ull;
#pragma unroll
            for (int nt = 0; nt < 4; ++nt) {
              int v = v0 + nt * 16 + lr;
              if (v < Vn) {
                u64 kk = ((u64)mono(acc[mt][nt][j]) << 32) | (u64)(unsigned)(~v);
                if (kk > k) k = kk;
              }
            }
#pragma unroll
            for (int off = 1; off < 16; off <<= 1) {
              u64 o = shfl_xor_u64(k, off);
              if (o > k) k = o;
            }
            if (lr == 0) {
              int b = rows0 + mt * 16 + hi4 * 4 + j;
              atomicMax(&amax[(size_t)t * Bn + b], k);
            }
          }
      }
    }
    if (t != Tn - 1) { nb += 1; gridbar<false>(flags, xdone, go, nb); }
  }
}

// ---------------------------------------------------------------------------
extern "C" void kernel_launch(void* const* d_in, const int* in_sizes, int n_in,
                              void* d_out, int out_size, void* d_ws, size_t ws_size,
                              hipStream_t stream) {
  const float* enc      = (const float*)d_in[0];
  const int*   lens     = (const int*)d_in[1];
  const float* emb      = (const float*)d_in[2];
  const float* w_ih     = (const float*)d_in[3];
  const float* w_hh     = (const float*)d_in[4];
  const float* b_ih     = (const float*)d_in[5];
  const float* b_hh     = (const float*)d_in[6];
  const float* attn_w   = (const float*)d_in[7];
  const float* concat_w = (const float*)d_in[8];
  const float* gamma    = (const float*)d_in[9];
  const float* beta     = (const float*)d_in[10];
  const float* proj_w   = (const float*)d_in[11];
  float* out = (float*)d_out;

  char* p = (char*)d_ws;
  auto alloc = [&](size_t bytes, size_t align) -> char* {
    uintptr_t a = ((uintptr_t)p + align - 1) & ~(uintptr_t)(align - 1);
    char* r = (char*)a;
    p = r + bytes;
    return r;
  };
  // barrier lines: 256 flags + 8 xdone + 8 go, 128B apart
  unsigned* flags = (unsigned*)alloc(272 * 32 * 4, 128);
  unsigned* xdone = flags + 256 * 32;
  unsigned* go    = xdone + 8 * 32;
  u64* amax  = (u64*)alloc((size_t)Tn * Bn * 8, 8);
  float* h32 = (float*)alloc((size_t)2 * Bn * Hn * 4, 4);
  float* c32 = (float*)alloc((size_t)2 * Bn * Hn * 4, 4);
  float* awT = (float*)alloc((size_t)Hn * Hn * 4, 4);
  float* cwT = (float*)alloc((size_t)2 * Hn * Hn * 4, 4);
  float* biasc = (float*)alloc((size_t)4 * Hn * 4, 4);
  u32* hhl = (u32*)alloc((size_t)2 * Bn * Hn * 4, 8);
  u32* thl = (u32*)alloc((size_t)Bn * Hn * 4, 8);
  u16* wch = (u16*)alloc((size_t)4 * Hn * 448 * 2, 8);
  u16* wcl = (u16*)alloc((size_t)4 * Hn * 448 * 2, 8);
  u16* ebh = (u16*)alloc((size_t)Vn * En * 2, 8);
  u16* ebl = (u16*)alloc((size_t)Vn * En * 2, 8);
  u16* pwh = (u16*)alloc((size_t)Vn * Hn * 2, 8);
  u16* pwl = (u16*)alloc((size_t)Vn * Hn * 2, 8);

  k_zero<<<8, 1024, 0, stream>>>(flags, 272 * 32);
  k_all<<<G, BT, 0, stream>>>(enc, lens, emb, w_ih, w_hh, b_ih, b_hh,
                              attn_w, concat_w, gamma, beta, proj_w, out,
                              flags, xdone, go, h32, c32, awT, cwT, biasc,
                              amax, hhl, thl,
                              wch, wcl, ebh, ebl, pwh, pwl);
}

// Round 10
// 1481.836 us; speedup vs baseline: 1.1314x; 1.1314x over previous
//
#include <hip/hip_runtime.h>

// PathDecoder: B=256, L=192, H=320, E=128, V=27000, T=8
constexpr int Bn = 256;
constexpr int Ln = 192;
constexpr int Hn = 320;
constexpr int En = 128;
constexpr int Vn = 27000;
constexpr int Tn = 8;
constexpr float NEGV   = -1e9f;
constexpr float LN_EPS = 1e-5f;
constexpr int G  = 256;   // workgroups (<=256 CUs -> co-resident)
constexpr int BT = 512;   // 8 waves

typedef __attribute__((ext_vector_type(8))) short bf16x8;
typedef __attribute__((ext_vector_type(4))) float f32x4;
typedef unsigned long long u64;
typedef unsigned int u32;
typedef unsigned short u16;

__device__ __forceinline__ float sigmoidf_(float x) { return 1.f / (1.f + expf(-x)); }
__device__ __forceinline__ u16 f2bf(float x) {
  unsigned u = __float_as_uint(x);
  return (u16)((u + 0x7fffu + ((u >> 16) & 1u)) >> 16);
}
__device__ __forceinline__ float bf2f(u16 h) { return __uint_as_float((unsigned)h << 16); }
__device__ __forceinline__ unsigned mono(float f) {
  unsigned u = __float_as_uint(f);
  return (u & 0x80000000u) ? ~u : (u | 0x80000000u);
}
__device__ __forceinline__ u64 shfl_xor_u64(u64 x, int off) {
  unsigned lo = (unsigned)x, hi = (unsigned)(x >> 32);
  lo = __shfl_xor(lo, off, 64);
  hi = __shfl_xor(hi, off, 64);
  return ((u64)hi << 32) | lo;
}

#define AT_LD(p)    __hip_atomic_load((p), __ATOMIC_RELAXED, __HIP_MEMORY_SCOPE_AGENT)
#define AT_ST(p, v) __hip_atomic_store((p), (v), __ATOMIC_RELAXED, __HIP_MEMORY_SCOPE_AGENT)

template <int SLP>
__device__ __forceinline__ void spin(unsigned* p, unsigned e) {
  while (__hip_atomic_load(p, __ATOMIC_RELAXED, __HIP_MEMORY_SCOPE_AGENT) < e)
    __builtin_amdgcn_s_sleep(SLP);
}

// ---------------------------------------------------------------------------
// HEAVY global tree barrier (release/acquire) — used ONCE after prep.
__device__ void gridbar_heavy(unsigned* flags, unsigned* xdone, unsigned* go, unsigned e) {
  __syncthreads();
  const int bid = blockIdx.x, tid = threadIdx.x;
  if (bid >= 8) {
    if (tid == 0) {
      __hip_atomic_store(&flags[bid * 32], e, __ATOMIC_RELEASE, __HIP_MEMORY_SCOPE_AGENT);
      spin<8>(&go[(bid & 7) * 32], e);
      unsigned v = __hip_atomic_load(&go[(bid & 7) * 32], __ATOMIC_ACQUIRE, __HIP_MEMORY_SCOPE_AGENT);
      asm volatile("" :: "v"(v));
    }
    __syncthreads();
  } else if (bid != 0) {
    if (tid >= 1 && tid < 32) spin<4>(&flags[(bid + tid * 8) * 32], e);
    __syncthreads();
    if (tid == 0) {
      __hip_atomic_store(&xdone[bid * 32], e, __ATOMIC_RELEASE, __HIP_MEMORY_SCOPE_AGENT);
      spin<8>(&go[bid * 32], e);
      unsigned v = __hip_atomic_load(&go[bid * 32], __ATOMIC_ACQUIRE, __HIP_MEMORY_SCOPE_AGENT);
      asm volatile("" :: "v"(v));
    }
    __syncthreads();
  } else {
    if (tid >= 1 && tid < 32) spin<4>(&flags[(tid * 8) * 32], e);
    if (tid >= 32 && tid < 39) spin<4>(&xdone[(tid - 31) * 32], e);
    __syncthreads();
    if (tid < 8) {
      unsigned v = __hip_atomic_load(&xdone[((tid == 0) ? 1 : tid) * 32],
                                     __ATOMIC_ACQUIRE, __HIP_MEMORY_SCOPE_AGENT);
      asm volatile("" :: "v"(v));
      __hip_atomic_store(&go[tid * 32], e, __ATOMIC_RELEASE, __HIP_MEMORY_SCOPE_AGENT);
    }
    __syncthreads();
  }
}

// Pod-local barrier: 64 blocks of pod p. Relaxed flags only; data travels via
// agent-relaxed atomics (LLC-coherent). Leader = bid == pod*8.
__device__ __forceinline__ void podbar(unsigned* flags, unsigned* podgo, int pod, unsigned e) {
  __syncthreads();
  const int bid = blockIdx.x, tid = threadIdx.x;
  if (bid != pod * 8) {
    if (tid == 0) {
      AT_ST(&flags[bid * 32], e);
      spin<8>(&podgo[pod * 32], e);
    }
    __syncthreads();
  } else {
    if (tid >= 1 && tid < 64) {
      int i = tid;
      int mb_ = (i & 7) | (pod << 3) | ((i >> 3) << 5);
      spin<4>(&flags[mb_ * 32], e);
    }
    __syncthreads();
    if (tid == 0) AT_ST(&podgo[pod * 32], e);
    __syncthreads();
  }
}

__global__ __launch_bounds__(1024) void k_zero(unsigned* flags, int n) {
  for (int i = blockIdx.x * 1024 + threadIdx.x; i < n; i += gridDim.x * 1024) flags[i] = 0u;
}

// ---------------------------------------------------------------------------
__global__ __launch_bounds__(BT, 2) void k_all(
    const float* __restrict__ enc, const int* __restrict__ lens,
    const float* __restrict__ emb,
    const float* __restrict__ w_ih, const float* __restrict__ w_hh,
    const float* __restrict__ b_ih, const float* __restrict__ b_hh,
    const float* __restrict__ attn_w, const float* __restrict__ concat_w,
    const float* __restrict__ gamma, const float* __restrict__ beta,
    const float* __restrict__ proj_w, float* __restrict__ out,
    unsigned* flags, unsigned* xdone, unsigned* go, unsigned* podgo,
    float* h32, float* c32, float* awT, float* cwT, float* biasc,
    u64* amax, u32* hhl, u32* thl,
    u16* wch, u16* wcl, u16* ebh, u16* ebl, u16* pwh, u16* pwl) {
  __shared__ float eL[64 * Hn];        // 80 KB: enc chunk (attn) / A-panel (proj)
  __shared__ float hs[Hn], ahs[Hn], cts[Hn];
  __shared__ float sc[64];
  __shared__ float rmS, rsS, rfS, rmu, rvar;

  const int bid = blockIdx.x, tid = threadIdx.x;
  const int wv = tid >> 6, lane = tid & 63;
  const int gid = bid * BT + tid;
  const int NT = G * BT;
  const size_t HB = (size_t)Bn * Hn;
  // pod decomposition: 4 independent 64-row pipelines
  const int xcd = bid & 7, pod = (bid >> 3) & 3, slot = bid >> 5;
  const int prow = xcd * 8 + slot;          // row within panel, 0..63
  const int b_row = pod * 64 + prow;        // this block's attn row
  unsigned nb = 0;

  // ================= phase 0: one-time prep (normal stores; heavy barrier) ===
  for (int i = gid; i < Vn * Hn / 4; i += NT) {
    float4 v = ((const float4*)proj_w)[i];
    u16 h0_ = f2bf(v.x), h1_ = f2bf(v.y), h2_ = f2bf(v.z), h3_ = f2bf(v.w);
    ((ushort4*)pwh)[i] = make_ushort4(h0_, h1_, h2_, h3_);
    ((ushort4*)pwl)[i] = make_ushort4(f2bf(v.x - bf2f(h0_)), f2bf(v.y - bf2f(h1_)),
                                      f2bf(v.z - bf2f(h2_)), f2bf(v.w - bf2f(h3_)));
  }
  for (int i = gid; i < Vn * En / 4; i += NT) {
    float4 v = ((const float4*)emb)[i];
    u16 h0_ = f2bf(v.x), h1_ = f2bf(v.y), h2_ = f2bf(v.z), h3_ = f2bf(v.w);
    ((ushort4*)ebh)[i] = make_ushort4(h0_, h1_, h2_, h3_);
    ((ushort4*)ebl)[i] = make_ushort4(f2bf(v.x - bf2f(h0_)), f2bf(v.y - bf2f(h1_)),
                                      f2bf(v.z - bf2f(h2_)), f2bf(v.w - bf2f(h3_)));
  }
  for (int i = gid; i < 4 * Hn * 112; i += NT) {  // w_cat [1280][448] split
    int r = i / 112, k = (i % 112) * 4;
    const float* src = (k < En) ? (w_ih + (size_t)r * En + k)
                                : (w_hh + (size_t)r * Hn + (k - En));
    float4 v = *(const float4*)src;
    size_t o = (size_t)r * 448 + k;
    u16 h0_ = f2bf(v.x), h1_ = f2bf(v.y), h2_ = f2bf(v.z), h3_ = f2bf(v.w);
    *(ushort4*)(wch + o) = make_ushort4(h0_, h1_, h2_, h3_);
    *(ushort4*)(wcl + o) = make_ushort4(f2bf(v.x - bf2f(h0_)), f2bf(v.y - bf2f(h1_)),
                                        f2bf(v.z - bf2f(h2_)), f2bf(v.w - bf2f(h3_)));
  }
  for (int i = gid; i < Hn * Hn; i += NT) {       // awT[k][j] = attn_w[j][k]
    int k = i / Hn, j = i % Hn;
    awT[i] = attn_w[(size_t)j * Hn + k];
  }
  for (int i = gid; i < 2 * Hn * Hn; i += NT) {   // cwT[k][j] = concat_w[j][k]
    int k = i / Hn, j = i % Hn;
    cwT[i] = concat_w[(size_t)j * (2 * Hn) + k];
  }
  for (int i = gid; i < 4 * Hn; i += NT) biasc[i] = b_ih[i] + b_hh[i];
  for (int i = gid; i < Tn * Bn; i += NT) amax[i] = 0ull;
  {
    if (tid < Hn) {
      const float* p = enc + (size_t)bid * Ln * Hn + tid;
      float s = 0.f;
#pragma unroll 4
      for (int l = 0; l < Ln; ++l) s += p[(size_t)l * Hn];
      float hv = s / (float)lens[bid];
      size_t o = (size_t)bid * Hn + tid;
      h32[o] = hv; c32[o] = hv;
      u16 hb = f2bf(hv), lb = f2bf(hv - bf2f(hb));
      hhl[o] = (u32)hb | ((u32)lb << 16);
    }
  }
  nb += 1; gridbar_heavy(flags, xdone, go, nb);   // ONE heavy barrier

  // ================= decode steps (per-pod independent pipelines) ===========
  for (int t = 0; t < Tn; ++t) {
    const int hin = t & 1, hout = hin ^ 1;

    // ---- phase A: gates GEMM (split-bf16 MFMA) + LSTM cell ----
    // per pod: 40 wave-tiles (20 j-cols x 2 row-halves of 32), on slot==0 blocks
    if (slot == 0 && wv < 5) {
      int tcand = xcd * 5 + wv;               // 0..39
      int j0 = (tcand % 20) * 16;
      int rh = tcand / 20;
      int b0 = pod * 64 + rh * 32;
      int lr = lane & 15, hi4 = lane >> 4, kg = hi4 * 8;
      int tkr[2];
#pragma unroll
      for (int mt = 0; mt < 2; ++mt) {
        int r = b0 + mt * 16 + lr;
        if (t == 0) tkr[mt] = 1;
        else {
          u64 a = AT_LD(&amax[(size_t)(t - 1) * Bn + r]);
          tkr[mt] = (int)(~(unsigned)a);
        }
      }
      f32x4 acc[2][4];
#pragma unroll
      for (int i = 0; i < 2; ++i)
#pragma unroll
        for (int j = 0; j < 4; ++j) acc[i][j] = (f32x4){0.f, 0.f, 0.f, 0.f};
      const u32* hin_p = hhl + (size_t)hin * HB;
      for (int k0 = 0; k0 < 448; k0 += 32) {
        bf16x8 af[2][2], bw[4][2];
#pragma unroll
        for (int mt = 0; mt < 2; ++mt) {
          int r = b0 + mt * 16 + lr;
          if (k0 < En) {
            size_t o = (size_t)tkr[mt] * En + k0 + kg;
            af[mt][0] = *(const bf16x8*)(ebh + o);
            af[mt][1] = *(const bf16x8*)(ebl + o);
          } else {
            size_t o = (size_t)r * Hn + (k0 - En) + kg;
            u32 w[8];
#pragma unroll
            for (int q = 0; q < 8; ++q) w[q] = AT_LD((u32*)&hin_p[o + q]);
#pragma unroll
            for (int q = 0; q < 8; ++q) {
              af[mt][0][q] = (short)(w[q] & 0xffffu);
              af[mt][1][q] = (short)(w[q] >> 16);
            }
          }
        }
#pragma unroll
        for (int g = 0; g < 4; ++g) {
          size_t o = (size_t)(g * Hn + j0 + lr) * 448 + k0 + kg;
          bw[g][0] = *(const bf16x8*)(wch + o);
          bw[g][1] = *(const bf16x8*)(wcl + o);
        }
#pragma unroll
        for (int mt = 0; mt < 2; ++mt)
#pragma unroll
          for (int g = 0; g < 4; ++g) {
            acc[mt][g] = __builtin_amdgcn_mfma_f32_16x16x32_bf16(af[mt][0], bw[g][0], acc[mt][g], 0, 0, 0);
            acc[mt][g] = __builtin_amdgcn_mfma_f32_16x16x32_bf16(af[mt][0], bw[g][1], acc[mt][g], 0, 0, 0);
            acc[mt][g] = __builtin_amdgcn_mfma_f32_16x16x32_bf16(af[mt][1], bw[g][0], acc[mt][g], 0, 0, 0);
          }
      }
      int jc = j0 + lr;
      const float* c_i = c32 + (size_t)hin * HB;   // same wave wrote it last step
      float* c_o = c32 + (size_t)hout * HB;
#pragma unroll
      for (int mt = 0; mt < 2; ++mt)
#pragma unroll
        for (int j = 0; j < 4; ++j) {
          int b = b0 + mt * 16 + hi4 * 4 + j;
          float iv = acc[mt][0][j] + biasc[jc];
          float fv = acc[mt][1][j] + biasc[Hn + jc];
          float gv = acc[mt][2][j] + biasc[2 * Hn + jc];
          float ov = acc[mt][3][j] + biasc[3 * Hn + jc];
          float co = c_i[(size_t)b * Hn + jc];
          float cn = sigmoidf_(fv) * co + sigmoidf_(iv) * tanhf(gv);
          float hn = sigmoidf_(ov) * tanhf(cn);
          size_t o = (size_t)b * Hn + jc;
          c_o[o] = cn;
          AT_ST(&h32[(size_t)hout * HB + o], hn);
          u16 hb = f2bf(hn), lb = f2bf(hn - bf2f(hb));
          AT_ST(&hhl[(size_t)hout * HB + o], (u32)hb | ((u32)lb << 16));
        }
    }
    nb += 1; podbar(flags, podgo, pod, nb);

    // ---- phase B: attention (online softmax) + cat + LN for row b_row ----
    {
      int b = b_row;
      if (tid < Hn) hs[tid] = AT_LD(&h32[(size_t)hout * HB + (size_t)b * Hn + tid]);
      __syncthreads();
      if (tid < Hn) {
        float s = 0.f;
#pragma unroll 8
        for (int k = 0; k < Hn; ++k) s += awT[(size_t)k * Hn + tid] * hs[k];
        ahs[tid] = s;
      }
      if (tid == 0) { rmS = -3.402823466e38f; rsS = 0.f; }
      __syncthreads();

      int len = lens[b];
      float ctxacc = 0.f;
      const float* encB = enc + (size_t)b * Ln * Hn;
      for (int c = 0; c < 3; ++c) {
        const float4* src = (const float4*)(encB + (size_t)c * 64 * Hn);
#pragma unroll
        for (int i = 0; i < 10; ++i) ((float4*)eL)[tid + i * BT] = src[tid + i * BT];
        __syncthreads();
#pragma unroll
        for (int r = 0; r < 8; ++r) {
          int l = wv * 8 + r;
          float s = 0.f;
#pragma unroll
          for (int c5 = 0; c5 < 5; ++c5)
            s += eL[l * Hn + lane + 64 * c5] * ahs[lane + 64 * c5];
#pragma unroll
          for (int off = 32; off > 0; off >>= 1) s += __shfl_xor(s, off, 64);
          if (lane == 0) sc[l] = s + ((c * 64 + l < len) ? 0.f : NEGV);
        }
        __syncthreads();
        if (wv == 0) {
          float v = sc[lane];
          float m = v;
#pragma unroll
          for (int off = 32; off > 0; off >>= 1) m = fmaxf(m, __shfl_xor(m, off, 64));
          float oldm = rmS;
          float newm = fmaxf(oldm, m);
          float p = expf(v - newm);
          sc[lane] = p;
          float s = p;
#pragma unroll
          for (int off = 32; off > 0; off >>= 1) s += __shfl_xor(s, off, 64);
          if (lane == 0) {
            float f = expf(oldm - newm);
            rfS = f;
            rsS = rsS * f + s;
            rmS = newm;
          }
        }
        __syncthreads();
        if (tid < Hn) {
          float f = rfS;
          float a = 0.f;
#pragma unroll 8
          for (int l = 0; l < 64; ++l) a += sc[l] * eL[l * Hn + tid];
          ctxacc = ctxacc * f + a;
        }
        __syncthreads();
      }
      if (tid < Hn) cts[tid] = ctxacc / rsS;
      __syncthreads();

      float catv = 0.f;
      if (tid < Hn) {
        float s = 0.f;
#pragma unroll 8
        for (int k = 0; k < Hn; ++k) s += cwT[(size_t)k * Hn + tid] * hs[k];
#pragma unroll 8
        for (int k = 0; k < Hn; ++k) s += cwT[(size_t)(Hn + k) * Hn + tid] * cts[k];
        catv = s;
        ahs[tid] = s;
      }
      __syncthreads();
      if (tid < 64) {
        float s1 = 0.f, s2 = 0.f;
        for (int i = tid; i < Hn; i += 64) { float v = ahs[i]; s1 += v; s2 += v * v; }
#pragma unroll
        for (int off = 32; off > 0; off >>= 1) {
          s1 += __shfl_xor(s1, off, 64);
          s2 += __shfl_xor(s2, off, 64);
        }
        if (tid == 0) {
          float mu = s1 * (1.f / 320.f);
          rmu = mu;
          rvar = s2 * (1.f / 320.f) - mu * mu;
        }
      }
      __syncthreads();
      if (tid < Hn) {
        float rstd = 1.f / sqrtf(rvar + LN_EPS);
        float y = (catv - rmu) * rstd * gamma[tid] + beta[tid];
        float tv = tanhf(y);
        u16 tb = f2bf(tv), lb = f2bf(tv - bf2f(tb));
        AT_ST(&thl[(size_t)b * Hn + tid], (u32)tb | ((u32)lb << 16));
      }
    }
    nb += 1; podbar(flags, podgo, pod, nb);

    // ---- phase C: projection (split-bf16 MFMA) + fused argmax ----
    // pod panel rows0 = pod*64; wave vb = xcd*53 + (slot*8 + wv) if < 422
    {
      const int rows0 = pod * 64;
      u16* Ahi = (u16*)eL;
      u16* Alo = Ahi + 64 * Hn;

      // stage A-panel (pod's 64 rows of thl) into LDS, split hi/lo, swizzled
      for (int i = tid; i < 64 * Hn / 4; i += BT) {
        int r = i / (Hn / 4);
        int k = (i % (Hn / 4)) * 4;
        u32 w0 = AT_LD(&thl[(size_t)(rows0 + r) * Hn + k + 0]);
        u32 w1 = AT_LD(&thl[(size_t)(rows0 + r) * Hn + k + 1]);
        u32 w2 = AT_LD(&thl[(size_t)(rows0 + r) * Hn + k + 2]);
        u32 w3 = AT_LD(&thl[(size_t)(rows0 + r) * Hn + k + 3]);
        int off = ((r * Hn + k) * 2) ^ ((r & 7) << 4);
        *(ushort4*)((char*)Ahi + off) =
            make_ushort4((u16)w0, (u16)w1, (u16)w2, (u16)w3);
        *(ushort4*)((char*)Alo + off) =
            make_ushort4((u16)(w0 >> 16), (u16)(w1 >> 16), (u16)(w2 >> 16), (u16)(w3 >> 16));
      }
      __syncthreads();

      int vb_idx = slot * 8 + wv;
      int vb = xcd * 53 + vb_idx;
      if (vb_idx < 53 && vb < 422) {
        int v0 = vb * 64;
        int lr = lane & 15, hi4 = lane >> 4, kg = hi4 * 8;
        f32x4 acc[4][4];
#pragma unroll
        for (int i = 0; i < 4; ++i)
#pragma unroll
          for (int j = 0; j < 4; ++j) acc[i][j] = (f32x4){0.f, 0.f, 0.f, 0.f};
        const bf16x8 zf = {0, 0, 0, 0, 0, 0, 0, 0};
        for (int k0 = 0; k0 < Hn; k0 += 32) {
          bf16x8 af[4][2], bw[4][2];
#pragma unroll
          for (int mt = 0; mt < 4; ++mt) {
            int rr = mt * 16 + lr;
            int off = ((rr * Hn + k0 + kg) * 2) ^ ((rr & 7) << 4);
            af[mt][0] = *(const bf16x8*)((char*)Ahi + off);
            af[mt][1] = *(const bf16x8*)((char*)Alo + off);
          }
#pragma unroll
          for (int nt = 0; nt < 4; ++nt) {
            int v = v0 + nt * 16 + lr;
            if (v < Vn) {
              size_t o = (size_t)v * Hn + k0 + kg;
              bw[nt][0] = *(const bf16x8*)(pwh + o);
              bw[nt][1] = *(const bf16x8*)(pwl + o);
            } else {
              bw[nt][0] = zf; bw[nt][1] = zf;
            }
          }
#pragma unroll
          for (int mt = 0; mt < 4; ++mt)
#pragma unroll
            for (int nt = 0; nt < 4; ++nt) {
              acc[mt][nt] = __builtin_amdgcn_mfma_f32_16x16x32_bf16(af[mt][0], bw[nt][0], acc[mt][nt], 0, 0, 0);
              acc[mt][nt] = __builtin_amdgcn_mfma_f32_16x16x32_bf16(af[mt][0], bw[nt][1], acc[mt][nt], 0, 0, 0);
              acc[mt][nt] = __builtin_amdgcn_mfma_f32_16x16x32_bf16(af[mt][1], bw[nt][0], acc[mt][nt], 0, 0, 0);
            }
        }
        float* ot = out + (size_t)t * Bn * Vn;
#pragma unroll
        for (int mt = 0; mt < 4; ++mt)
#pragma unroll
          for (int nt = 0; nt < 4; ++nt) {
            int v = v0 + nt * 16 + lr;
            if (v < Vn) {
#pragma unroll
              for (int j = 0; j < 4; ++j)
                __builtin_nontemporal_store(acc[mt][nt][j],
                    &ot[(size_t)(rows0 + mt * 16 + hi4 * 4 + j) * Vn + v]);
            }
          }
        // argmax: key = (mono(val)<<32) | ~idx ; max key == first max
#pragma unroll
        for (int mt = 0; mt < 4; ++mt)
#pragma unroll
          for (int j = 0; j < 4; ++j) {
            u64 k = 0ull;
#pragma unroll
            for (int nt = 0; nt < 4; ++nt) {
              int v = v0 + nt * 16 + lr;
              if (v < Vn) {
                u64 kk = ((u64)mono(acc[mt][nt][j]) << 32) | (u64)(unsigned)(~v);
                if (kk > k) k = kk;
              }
            }
#pragma unroll
            for (int off = 1; off < 16; off <<= 1) {
              u64 o = shfl_xor_u64(k, off);
              if (o > k) k = o;
            }
            if (lr == 0) {
              int b = rows0 + mt * 16 + hi4 * 4 + j;
              atomicMax(&amax[(size_t)t * Bn + b], k);
            }
          }
      }
    }
    if (t != Tn - 1) { nb += 1; podbar(flags, podgo, pod, nb); }
  }
}

// ---------------------------------------------------------------------------
extern "C" void kernel_launch(void* const* d_in, const int* in_sizes, int n_in,
                              void* d_out, int out_size, void* d_ws, size_t ws_size,
                              hipStream_t stream) {
  const float* enc      = (const float*)d_in[0];
  const int*   lens     = (const int*)d_in[1];
  const float* emb      = (const float*)d_in[2];
  const float* w_ih     = (const float*)d_in[3];
  const float* w_hh     = (const float*)d_in[4];
  const float* b_ih     = (const float*)d_in[5];
  const float* b_hh     = (const float*)d_in[6];
  const float* attn_w   = (const float*)d_in[7];
  const float* concat_w = (const float*)d_in[8];
  const float* gamma    = (const float*)d_in[9];
  const float* beta     = (const float*)d_in[10];
  const float* proj_w   = (const float*)d_in[11];
  float* out = (float*)d_out;

  char* p = (char*)d_ws;
  auto alloc = [&](size_t bytes, size_t align) -> char* {
    uintptr_t a = ((uintptr_t)p + align - 1) & ~(uintptr_t)(align - 1);
    char* r = (char*)a;
    p = r + bytes;
    return r;
  };
  // barrier lines: 256 flags + 8 xdone + 8 go + 4 podgo, 128B apart
  unsigned* flags = (unsigned*)alloc(276 * 32 * 4, 128);
  unsigned* xdone = flags + 256 * 32;
  unsigned* go    = xdone + 8 * 32;
  unsigned* podgo = go + 8 * 32;
  u64* amax  = (u64*)alloc((size_t)Tn * Bn * 8, 8);
  float* h32 = (float*)alloc((size_t)2 * Bn * Hn * 4, 4);
  float* c32 = (float*)alloc((size_t)2 * Bn * Hn * 4, 4);
  float* awT = (float*)alloc((size_t)Hn * Hn * 4, 4);
  float* cwT = (float*)alloc((size_t)2 * Hn * Hn * 4, 4);
  float* biasc = (float*)alloc((size_t)4 * Hn * 4, 4);
  u32* hhl = (u32*)alloc((size_t)2 * Bn * Hn * 4, 8);
  u32* thl = (u32*)alloc((size_t)Bn * Hn * 4, 8);
  u16* wch = (u16*)alloc((size_t)4 * Hn * 448 * 2, 8);
  u16* wcl = (u16*)alloc((size_t)4 * Hn * 448 * 2, 8);
  u16* ebh = (u16*)alloc((size_t)Vn * En * 2, 8);
  u16* ebl = (u16*)alloc((size_t)Vn * En * 2, 8);
  u16* pwh = (u16*)alloc((size_t)Vn * Hn * 2, 8);
  u16* pwl = (u16*)alloc((size_t)Vn * Hn * 2, 8);

  k_zero<<<8, 1024, 0, stream>>>(flags, 276 * 32);
  k_all<<<G, BT, 0, stream>>>(enc, lens, emb, w_ih, w_hh, b_ih, b_hh,
                              attn_w, concat_w, gamma, beta, proj_w, out,
                              flags, xdone, go, podgo, h32, c32, awT, cwT, biasc,
                              amax, hhl, thl,
                              wch, wcl, ebh, ebl, pwh, pwl);
}

// Round 11
// 1481.637 us; speedup vs baseline: 1.1316x; 1.0001x over previous
//
#include <hip/hip_runtime.h>

// PathDecoder: B=256, L=192, H=320, E=128, V=27000, T=8
constexpr int Bn = 256;
constexpr int Ln = 192;
constexpr int Hn = 320;
constexpr int En = 128;
constexpr int Vn = 27000;
constexpr int Tn = 8;
constexpr float NEGV   = -1e9f;
constexpr float LN_EPS = 1e-5f;
constexpr int G  = 256;   // workgroups (<=256 CUs -> co-resident)
constexpr int BT = 512;   // 8 waves

typedef __attribute__((ext_vector_type(8))) short bf16x8;
typedef __attribute__((ext_vector_type(4))) float f32x4;
typedef unsigned long long u64;
typedef unsigned int u32;
typedef unsigned short u16;

__device__ __forceinline__ float sigmoidf_(float x) { return 1.f / (1.f + expf(-x)); }
__device__ __forceinline__ u16 f2bf(float x) {
  unsigned u = __float_as_uint(x);
  return (u16)((u + 0x7fffu + ((u >> 16) & 1u)) >> 16);
}
__device__ __forceinline__ float bf2f(u16 h) { return __uint_as_float((unsigned)h << 16); }
__device__ __forceinline__ unsigned mono(float f) {
  unsigned u = __float_as_uint(f);
  return (u & 0x80000000u) ? ~u : (u | 0x80000000u);
}
__device__ __forceinline__ u64 shfl_xor_u64(u64 x, int off) {
  unsigned lo = (unsigned)x, hi = (unsigned)(x >> 32);
  lo = __shfl_xor(lo, off, 64);
  hi = __shfl_xor(hi, off, 64);
  return ((u64)hi << 32) | lo;
}

#define AT_LD(p)    __hip_atomic_load((p), __ATOMIC_RELAXED, __HIP_MEMORY_SCOPE_AGENT)
#define AT_ST(p, v) __hip_atomic_store((p), (v), __ATOMIC_RELAXED, __HIP_MEMORY_SCOPE_AGENT)

template <int SLP>
__device__ __forceinline__ void spin(unsigned* p, unsigned e) {
  while (__hip_atomic_load(p, __ATOMIC_RELAXED, __HIP_MEMORY_SCOPE_AGENT) < e)
    __builtin_amdgcn_s_sleep(SLP);
}

// Busy spin: keeps the SIMD issuing VALU ops between polls so the DPM/DVFS
// governor holds high clocks (s_sleep signals "idle" -> downclock).
__device__ __forceinline__ void busy_spin(unsigned* p, unsigned e) {
  float x = (float)(threadIdx.x + 1);
  while (__hip_atomic_load(p, __ATOMIC_RELAXED, __HIP_MEMORY_SCOPE_AGENT) < e) {
#pragma unroll
    for (int i = 0; i < 64; ++i) x = __builtin_fmaf(x, 1.0000001f, 1e-7f);
    asm volatile("" :: "v"(x));
  }
}

// ---------------------------------------------------------------------------
// HEAVY global tree barrier (release/acquire) — used ONCE after prep.
__device__ void gridbar_heavy(unsigned* flags, unsigned* xdone, unsigned* go, unsigned e) {
  __syncthreads();
  const int bid = blockIdx.x, tid = threadIdx.x;
  if (bid >= 8) {
    if (tid == 0) {
      __hip_atomic_store(&flags[bid * 32], e, __ATOMIC_RELEASE, __HIP_MEMORY_SCOPE_AGENT);
      spin<8>(&go[(bid & 7) * 32], e);
      unsigned v = __hip_atomic_load(&go[(bid & 7) * 32], __ATOMIC_ACQUIRE, __HIP_MEMORY_SCOPE_AGENT);
      asm volatile("" :: "v"(v));
    }
    __syncthreads();
  } else if (bid != 0) {
    if (tid >= 1 && tid < 32) spin<4>(&flags[(bid + tid * 8) * 32], e);
    __syncthreads();
    if (tid == 0) {
      __hip_atomic_store(&xdone[bid * 32], e, __ATOMIC_RELEASE, __HIP_MEMORY_SCOPE_AGENT);
      spin<8>(&go[bid * 32], e);
      unsigned v = __hip_atomic_load(&go[bid * 32], __ATOMIC_ACQUIRE, __HIP_MEMORY_SCOPE_AGENT);
      asm volatile("" :: "v"(v));
    }
    __syncthreads();
  } else {
    if (tid >= 1 && tid < 32) spin<4>(&flags[(tid * 8) * 32], e);
    if (tid >= 32 && tid < 39) spin<4>(&xdone[(tid - 31) * 32], e);
    __syncthreads();
    if (tid < 8) {
      unsigned v = __hip_atomic_load(&xdone[((tid == 0) ? 1 : tid) * 32],
                                     __ATOMIC_ACQUIRE, __HIP_MEMORY_SCOPE_AGENT);
      asm volatile("" :: "v"(v));
      __hip_atomic_store(&go[tid * 32], e, __ATOMIC_RELEASE, __HIP_MEMORY_SCOPE_AGENT);
    }
    __syncthreads();
  }
}

// Pod-local barrier: 64 blocks of pod p; busy-wait (DVFS-friendly).
// ALL threads poll the pod's go line (one broadcast load per wave) with FMA
// filler. Leader gathers member flags with threads 1..63, then releases go.
__device__ __forceinline__ void podbar(unsigned* flags, unsigned* podgo, int pod, unsigned e) {
  __syncthreads();
  const int bid = blockIdx.x, tid = threadIdx.x;
  if (bid != pod * 8) {
    if (tid == 0) AT_ST(&flags[bid * 32], e);
  } else {
    if (tid >= 1 && tid < 64) {
      int mb_ = (tid & 7) | (pod << 3) | ((tid >> 3) << 5);
      busy_spin(&flags[mb_ * 32], e);
    }
    __syncthreads();          // all leader threads rendezvous BEFORE go-poll
    if (tid == 0) AT_ST(&podgo[pod * 32], e);
  }
  busy_spin(&podgo[pod * 32], e);
  __syncthreads();
}

__global__ __launch_bounds__(1024) void k_zero(unsigned* flags, int n) {
  for (int i = blockIdx.x * 1024 + threadIdx.x; i < n; i += gridDim.x * 1024) flags[i] = 0u;
}

// ---------------------------------------------------------------------------
__global__ __launch_bounds__(BT, 2) void k_all(
    const float* __restrict__ enc, const int* __restrict__ lens,
    const float* __restrict__ emb,
    const float* __restrict__ w_ih, const float* __restrict__ w_hh,
    const float* __restrict__ b_ih, const float* __restrict__ b_hh,
    const float* __restrict__ attn_w, const float* __restrict__ concat_w,
    const float* __restrict__ gamma, const float* __restrict__ beta,
    const float* __restrict__ proj_w, float* __restrict__ out,
    unsigned* flags, unsigned* xdone, unsigned* go, unsigned* podgo,
    float* h32, float* c32, float* awT, float* cwT, float* biasc,
    u64* amax, u32* hhl, u32* thl,
    u16* wch, u16* wcl, u16* ebh, u16* ebl, u16* pwh, u16* pwl) {
  __shared__ float eL[64 * Hn];        // 80 KB: enc chunk (attn) / A-panel (proj)
  __shared__ float hs[Hn], ahs[Hn], cts[Hn];
  __shared__ float sc[64];
  __shared__ float rmS, rsS, rfS, rmu, rvar;

  const int bid = blockIdx.x, tid = threadIdx.x;
  const int wv = tid >> 6, lane = tid & 63;
  const int gid = bid * BT + tid;
  const int NT = G * BT;
  const size_t HB = (size_t)Bn * Hn;
  // pod decomposition: 4 independent 64-row pipelines
  const int xcd = bid & 7, pod = (bid >> 3) & 3, slot = bid >> 5;
  const int prow = xcd * 8 + slot;          // row within panel, 0..63
  const int b_row = pod * 64 + prow;        // this block's attn row
  unsigned nb = 0;

  // ================= phase 0: one-time prep (normal stores; heavy barrier) ===
  for (int i = gid; i < Vn * Hn / 4; i += NT) {
    float4 v = ((const float4*)proj_w)[i];
    u16 h0_ = f2bf(v.x), h1_ = f2bf(v.y), h2_ = f2bf(v.z), h3_ = f2bf(v.w);
    ((ushort4*)pwh)[i] = make_ushort4(h0_, h1_, h2_, h3_);
    ((ushort4*)pwl)[i] = make_ushort4(f2bf(v.x - bf2f(h0_)), f2bf(v.y - bf2f(h1_)),
                                      f2bf(v.z - bf2f(h2_)), f2bf(v.w - bf2f(h3_)));
  }
  for (int i = gid; i < Vn * En / 4; i += NT) {
    float4 v = ((const float4*)emb)[i];
    u16 h0_ = f2bf(v.x), h1_ = f2bf(v.y), h2_ = f2bf(v.z), h3_ = f2bf(v.w);
    ((ushort4*)ebh)[i] = make_ushort4(h0_, h1_, h2_, h3_);
    ((ushort4*)ebl)[i] = make_ushort4(f2bf(v.x - bf2f(h0_)), f2bf(v.y - bf2f(h1_)),
                                      f2bf(v.z - bf2f(h2_)), f2bf(v.w - bf2f(h3_)));
  }
  for (int i = gid; i < 4 * Hn * 112; i += NT) {  // w_cat [1280][448] split
    int r = i / 112, k = (i % 112) * 4;
    const float* src = (k < En) ? (w_ih + (size_t)r * En + k)
                                : (w_hh + (size_t)r * Hn + (k - En));
    float4 v = *(const float4*)src;
    size_t o = (size_t)r * 448 + k;
    u16 h0_ = f2bf(v.x), h1_ = f2bf(v.y), h2_ = f2bf(v.z), h3_ = f2bf(v.w);
    *(ushort4*)(wch + o) = make_ushort4(h0_, h1_, h2_, h3_);
    *(ushort4*)(wcl + o) = make_ushort4(f2bf(v.x - bf2f(h0_)), f2bf(v.y - bf2f(h1_)),
                                        f2bf(v.z - bf2f(h2_)), f2bf(v.w - bf2f(h3_)));
  }
  for (int i = gid; i < Hn * Hn; i += NT) {       // awT[k][j] = attn_w[j][k]
    int k = i / Hn, j = i % Hn;
    awT[i] = attn_w[(size_t)j * Hn + k];
  }
  for (int i = gid; i < 2 * Hn * Hn; i += NT) {   // cwT[k][j] = concat_w[j][k]
    int k = i / Hn, j = i % Hn;
    cwT[i] = concat_w[(size_t)j * (2 * Hn) + k];
  }
  for (int i = gid; i < 4 * Hn; i += NT) biasc[i] = b_ih[i] + b_hh[i];
  for (int i = gid; i < Tn * Bn; i += NT) amax[i] = 0ull;
  {
    if (tid < Hn) {
      const float* p = enc + (size_t)bid * Ln * Hn + tid;
      float s = 0.f;
#pragma unroll 4
      for (int l = 0; l < Ln; ++l) s += p[(size_t)l * Hn];
      float hv = s / (float)lens[bid];
      size_t o = (size_t)bid * Hn + tid;
      h32[o] = hv; c32[o] = hv;
      u16 hb = f2bf(hv), lb = f2bf(hv - bf2f(hb));
      hhl[o] = (u32)hb | ((u32)lb << 16);
    }
  }
  nb += 1; gridbar_heavy(flags, xdone, go, nb);   // ONE heavy barrier

  // ================= decode steps (per-pod independent pipelines) ===========
  for (int t = 0; t < Tn; ++t) {
    const int hin = t & 1, hout = hin ^ 1;

    // ---- phase A: gates GEMM (split-bf16 MFMA) + LSTM cell ----
    // per pod: 40 wave-tiles (20 j-cols x 2 row-halves of 32), on slot==0 blocks
    if (slot == 0 && wv < 5) {
      int tcand = xcd * 5 + wv;               // 0..39
      int j0 = (tcand % 20) * 16;
      int rh = tcand / 20;
      int b0 = pod * 64 + rh * 32;
      int lr = lane & 15, hi4 = lane >> 4, kg = hi4 * 8;
      int tkr[2];
#pragma unroll
      for (int mt = 0; mt < 2; ++mt) {
        int r = b0 + mt * 16 + lr;
        if (t == 0) tkr[mt] = 1;
        else {
          u64 a = AT_LD(&amax[(size_t)(t - 1) * Bn + r]);
          tkr[mt] = (int)(~(unsigned)a);
        }
      }
      f32x4 acc[2][4];
#pragma unroll
      for (int i = 0; i < 2; ++i)
#pragma unroll
        for (int j = 0; j < 4; ++j) acc[i][j] = (f32x4){0.f, 0.f, 0.f, 0.f};
      const u32* hin_p = hhl + (size_t)hin * HB;
      for (int k0 = 0; k0 < 448; k0 += 32) {
        bf16x8 af[2][2], bw[4][2];
#pragma unroll
        for (int mt = 0; mt < 2; ++mt) {
          int r = b0 + mt * 16 + lr;
          if (k0 < En) {
            size_t o = (size_t)tkr[mt] * En + k0 + kg;
            af[mt][0] = *(const bf16x8*)(ebh + o);
            af[mt][1] = *(const bf16x8*)(ebl + o);
          } else {
            size_t o = (size_t)r * Hn + (k0 - En) + kg;
            u32 w[8];
#pragma unroll
            for (int q = 0; q < 8; ++q) w[q] = AT_LD((u32*)&hin_p[o + q]);
#pragma unroll
            for (int q = 0; q < 8; ++q) {
              af[mt][0][q] = (short)(w[q] & 0xffffu);
              af[mt][1][q] = (short)(w[q] >> 16);
            }
          }
        }
#pragma unroll
        for (int g = 0; g < 4; ++g) {
          size_t o = (size_t)(g * Hn + j0 + lr) * 448 + k0 + kg;
          bw[g][0] = *(const bf16x8*)(wch + o);
          bw[g][1] = *(const bf16x8*)(wcl + o);
        }
#pragma unroll
        for (int mt = 0; mt < 2; ++mt)
#pragma unroll
          for (int g = 0; g < 4; ++g) {
            acc[mt][g] = __builtin_amdgcn_mfma_f32_16x16x32_bf16(af[mt][0], bw[g][0], acc[mt][g], 0, 0, 0);
            acc[mt][g] = __builtin_amdgcn_mfma_f32_16x16x32_bf16(af[mt][0], bw[g][1], acc[mt][g], 0, 0, 0);
            acc[mt][g] = __builtin_amdgcn_mfma_f32_16x16x32_bf16(af[mt][1], bw[g][0], acc[mt][g], 0, 0, 0);
          }
      }
      int jc = j0 + lr;
      const float* c_i = c32 + (size_t)hin * HB;   // same wave wrote it last step
      float* c_o = c32 + (size_t)hout * HB;
#pragma unroll
      for (int mt = 0; mt < 2; ++mt)
#pragma unroll
        for (int j = 0; j < 4; ++j) {
          int b = b0 + mt * 16 + hi4 * 4 + j;
          float iv = acc[mt][0][j] + biasc[jc];
          float fv = acc[mt][1][j] + biasc[Hn + jc];
          float gv = acc[mt][2][j] + biasc[2 * Hn + jc];
          float ov = acc[mt][3][j] + biasc[3 * Hn + jc];
          float co = c_i[(size_t)b * Hn + jc];
          float cn = sigmoidf_(fv) * co + sigmoidf_(iv) * tanhf(gv);
          float hn = sigmoidf_(ov) * tanhf(cn);
          size_t o = (size_t)b * Hn + jc;
          c_o[o] = cn;
          AT_ST(&h32[(size_t)hout * HB + o], hn);
          u16 hb = f2bf(hn), lb = f2bf(hn - bf2f(hb));
          AT_ST(&hhl[(size_t)hout * HB + o], (u32)hb | ((u32)lb << 16));
        }
    }
    nb += 1; podbar(flags, podgo, pod, nb);

    // ---- phase B: attention (online softmax) + cat + LN for row b_row ----
    {
      int b = b_row;
      if (tid < Hn) hs[tid] = AT_LD(&h32[(size_t)hout * HB + (size_t)b * Hn + tid]);
      __syncthreads();
      if (tid < Hn) {
        float s = 0.f;
#pragma unroll 8
        for (int k = 0; k < Hn; ++k) s += awT[(size_t)k * Hn + tid] * hs[k];
        ahs[tid] = s;
      }
      if (tid == 0) { rmS = -3.402823466e38f; rsS = 0.f; }
      __syncthreads();

      int len = lens[b];
      float ctxacc = 0.f;
      const float* encB = enc + (size_t)b * Ln * Hn;
      for (int c = 0; c < 3; ++c) {
        const float4* src = (const float4*)(encB + (size_t)c * 64 * Hn);
#pragma unroll
        for (int i = 0; i < 10; ++i) ((float4*)eL)[tid + i * BT] = src[tid + i * BT];
        __syncthreads();
#pragma unroll
        for (int r = 0; r < 8; ++r) {
          int l = wv * 8 + r;
          float s = 0.f;
#pragma unroll
          for (int c5 = 0; c5 < 5; ++c5)
            s += eL[l * Hn + lane + 64 * c5] * ahs[lane + 64 * c5];
#pragma unroll
          for (int off = 32; off > 0; off >>= 1) s += __shfl_xor(s, off, 64);
          if (lane == 0) sc[l] = s + ((c * 64 + l < len) ? 0.f : NEGV);
        }
        __syncthreads();
        if (wv == 0) {
          float v = sc[lane];
          float m = v;
#pragma unroll
          for (int off = 32; off > 0; off >>= 1) m = fmaxf(m, __shfl_xor(m, off, 64));
          float oldm = rmS;
          float newm = fmaxf(oldm, m);
          float p = expf(v - newm);
          sc[lane] = p;
          float s = p;
#pragma unroll
          for (int off = 32; off > 0; off >>= 1) s += __shfl_xor(s, off, 64);
          if (lane == 0) {
            float f = expf(oldm - newm);
            rfS = f;
            rsS = rsS * f + s;
            rmS = newm;
          }
        }
        __syncthreads();
        if (tid < Hn) {
          float f = rfS;
          float a = 0.f;
#pragma unroll 8
          for (int l = 0; l < 64; ++l) a += sc[l] * eL[l * Hn + tid];
          ctxacc = ctxacc * f + a;
        }
        __syncthreads();
      }
      if (tid < Hn) cts[tid] = ctxacc / rsS;
      __syncthreads();

      float catv = 0.f;
      if (tid < Hn) {
        float s = 0.f;
#pragma unroll 8
        for (int k = 0; k < Hn; ++k) s += cwT[(size_t)k * Hn + tid] * hs[k];
#pragma unroll 8
        for (int k = 0; k < Hn; ++k) s += cwT[(size_t)(Hn + k) * Hn + tid] * cts[k];
        catv = s;
        ahs[tid] = s;
      }
      __syncthreads();
      if (tid < 64) {
        float s1 = 0.f, s2 = 0.f;
        for (int i = tid; i < Hn; i += 64) { float v = ahs[i]; s1 += v; s2 += v * v; }
#pragma unroll
        for (int off = 32; off > 0; off >>= 1) {
          s1 += __shfl_xor(s1, off, 64);
          s2 += __shfl_xor(s2, off, 64);
        }
        if (tid == 0) {
          float mu = s1 * (1.f / 320.f);
          rmu = mu;
          rvar = s2 * (1.f / 320.f) - mu * mu;
        }
      }
      __syncthreads();
      if (tid < Hn) {
        float rstd = 1.f / sqrtf(rvar + LN_EPS);
        float y = (catv - rmu) * rstd * gamma[tid] + beta[tid];
        float tv = tanhf(y);
        u16 tb = f2bf(tv), lb = f2bf(tv - bf2f(tb));
        AT_ST(&thl[(size_t)b * Hn + tid], (u32)tb | ((u32)lb << 16));
      }
    }
    nb += 1; podbar(flags, podgo, pod, nb);

    // ---- phase C: projection (split-bf16 MFMA) + fused argmax ----
    // pod panel rows0 = pod*64; wave vb = xcd*53 + (slot*8 + wv) if < 422
    {
      const int rows0 = pod * 64;
      u16* Ahi = (u16*)eL;
      u16* Alo = Ahi + 64 * Hn;

      // stage A-panel (pod's 64 rows of thl) into LDS, split hi/lo, swizzled
      for (int i = tid; i < 64 * Hn / 4; i += BT) {
        int r = i / (Hn / 4);
        int k = (i % (Hn / 4)) * 4;
        u32 w0 = AT_LD(&thl[(size_t)(rows0 + r) * Hn + k + 0]);
        u32 w1 = AT_LD(&thl[(size_t)(rows0 + r) * Hn + k + 1]);
        u32 w2 = AT_LD(&thl[(size_t)(rows0 + r) * Hn + k + 2]);
        u32 w3 = AT_LD(&thl[(size_t)(rows0 + r) * Hn + k + 3]);
        int off = ((r * Hn + k) * 2) ^ ((r & 7) << 4);
        *(ushort4*)((char*)Ahi + off) =
            make_ushort4((u16)w0, (u16)w1, (u16)w2, (u16)w3);
        *(ushort4*)((char*)Alo + off) =
            make_ushort4((u16)(w0 >> 16), (u16)(w1 >> 16), (u16)(w2 >> 16), (u16)(w3 >> 16));
      }
      __syncthreads();

      int vb_idx = slot * 8 + wv;
      int vb = xcd * 53 + vb_idx;
      if (vb_idx < 53 && vb < 422) {
        int v0 = vb * 64;
        int lr = lane & 15, hi4 = lane >> 4, kg = hi4 * 8;
        f32x4 acc[4][4];
#pragma unroll
        for (int i = 0; i < 4; ++i)
#pragma unroll
          for (int j = 0; j < 4; ++j) acc[i][j] = (f32x4){0.f, 0.f, 0.f, 0.f};
        const bf16x8 zf = {0, 0, 0, 0, 0, 0, 0, 0};
        for (int k0 = 0; k0 < Hn; k0 += 32) {
          bf16x8 af[4][2], bw[4][2];
#pragma unroll
          for (int mt = 0; mt < 4; ++mt) {
            int rr = mt * 16 + lr;
            int off = ((rr * Hn + k0 + kg) * 2) ^ ((rr & 7) << 4);
            af[mt][0] = *(const bf16x8*)((char*)Ahi + off);
            af[mt][1] = *(const bf16x8*)((char*)Alo + off);
          }
#pragma unroll
          for (int nt = 0; nt < 4; ++nt) {
            int v = v0 + nt * 16 + lr;
            if (v < Vn) {
              size_t o = (size_t)v * Hn + k0 + kg;
              bw[nt][0] = *(const bf16x8*)(pwh + o);
              bw[nt][1] = *(const bf16x8*)(pwl + o);
            } else {
              bw[nt][0] = zf; bw[nt][1] = zf;
            }
          }
#pragma unroll
          for (int mt = 0; mt < 4; ++mt)
#pragma unroll
            for (int nt = 0; nt < 4; ++nt) {
              acc[mt][nt] = __builtin_amdgcn_mfma_f32_16x16x32_bf16(af[mt][0], bw[nt][0], acc[mt][nt], 0, 0, 0);
              acc[mt][nt] = __builtin_amdgcn_mfma_f32_16x16x32_bf16(af[mt][0], bw[nt][1], acc[mt][nt], 0, 0, 0);
              acc[mt][nt] = __builtin_amdgcn_mfma_f32_16x16x32_bf16(af[mt][1], bw[nt][0], acc[mt][nt], 0, 0, 0);
            }
        }
        float* ot = out + (size_t)t * Bn * Vn;
#pragma unroll
        for (int mt = 0; mt < 4; ++mt)
#pragma unroll
          for (int nt = 0; nt < 4; ++nt) {
            int v = v0 + nt * 16 + lr;
            if (v < Vn) {
#pragma unroll
              for (int j = 0; j < 4; ++j)
                __builtin_nontemporal_store(acc[mt][nt][j],
                    &ot[(size_t)(rows0 + mt * 16 + hi4 * 4 + j) * Vn + v]);
            }
          }
        // argmax: key = (mono(val)<<32) | ~idx ; max key == first max
#pragma unroll
        for (int mt = 0; mt < 4; ++mt)
#pragma unroll
          for (int j = 0; j < 4; ++j) {
            u64 k = 0ull;
#pragma unroll
            for (int nt = 0; nt < 4; ++nt) {
              int v = v0 + nt * 16 + lr;
              if (v < Vn) {
                u64 kk = ((u64)mono(acc[mt][nt][j]) << 32) | (u64)(unsigned)(~v);
                if (kk > k) k = kk;
              }
            }
#pragma unroll
            for (int off = 1; off < 16; off <<= 1) {
              u64 o = shfl_xor_u64(k, off);
              if (o > k) k = o;
            }
            if (lr == 0) {
              int b = rows0 + mt * 16 + hi4 * 4 + j;
              atomicMax(&amax[(size_t)t * Bn + b], k);
            }
          }
      }
    }
    if (t != Tn - 1) { nb += 1; podbar(flags, podgo, pod, nb); }
  }
}

// ---------------------------------------------------------------------------
extern "C" void kernel_launch(void* const* d_in, const int* in_sizes, int n_in,
                              void* d_out, int out_size, void* d_ws, size_t ws_size,
                              hipStream_t stream) {
  const float* enc      = (const float*)d_in[0];
  const int*   lens     = (const int*)d_in[1];
  const float* emb      = (const float*)d_in[2];
  const float* w_ih     = (const float*)d_in[3];
  const float* w_hh     = (const float*)d_in[4];
  const float* b_ih     = (const float*)d_in[5];
  const float* b_hh     = (const float*)d_in[6];
  const float* attn_w   = (const float*)d_in[7];
  const float* concat_w = (const float*)d_in[8];
  const float* gamma    = (const float*)d_in[9];
  const float* beta     = (const float*)d_in[10];
  const float* proj_w   = (const float*)d_in[11];
  float* out = (float*)d_out;

  char* p = (char*)d_ws;
  auto alloc = [&](size_t bytes, size_t align) -> char* {
    uintptr_t a = ((uintptr_t)p + align - 1) & ~(uintptr_t)(align - 1);
    char* r = (char*)a;
    p = r + bytes;
    return r;
  };
  // barrier lines: 256 flags + 8 xdone + 8 go + 4 podgo, 128B apart
  unsigned* flags = (unsigned*)alloc(276 * 32 * 4, 128);
  unsigned* xdone = flags + 256 * 32;
  unsigned* go    = xdone + 8 * 32;
  unsigned* podgo = go + 8 * 32;
  u64* amax  = (u64*)alloc((size_t)Tn * Bn * 8, 8);
  float* h32 = (float*)alloc((size_t)2 * Bn * Hn * 4, 4);
  float* c32 = (float*)alloc((size_t)2 * Bn * Hn * 4, 4);
  float* awT = (float*)alloc((size_t)Hn * Hn * 4, 4);
  float* cwT = (float*)alloc((size_t)2 * Hn * Hn * 4, 4);
  float* biasc = (float*)alloc((size_t)4 * Hn * 4, 4);
  u32* hhl = (u32*)alloc((size_t)2 * Bn * Hn * 4, 8);
  u32* thl = (u32*)alloc((size_t)Bn * Hn * 4, 8);
  u16* wch = (u16*)alloc((size_t)4 * Hn * 448 * 2, 8);
  u16* wcl = (u16*)alloc((size_t)4 * Hn * 448 * 2, 8);
  u16* ebh = (u16*)alloc((size_t)Vn * En * 2, 8);
  u16* ebl = (u16*)alloc((size_t)Vn * En * 2, 8);
  u16* pwh = (u16*)alloc((size_t)Vn * Hn * 2, 8);
  u16* pwl = (u16*)alloc((size_t)Vn * Hn * 2, 8);

  k_zero<<<8, 1024, 0, stream>>>(flags, 276 * 32);
  k_all<<<G, BT, 0, stream>>>(enc, lens, emb, w_ih, w_hh, b_ih, b_hh,
                              attn_w, concat_w, gamma, beta, proj_w, out,
                              flags, xdone, go, podgo, h32, c32, awT, cwT, biasc,
                              amax, hhl, thl,
                              wch, wcl, ebh, ebl, pwh, pwl);
}

// Round 12
// 1034.429 us; speedup vs baseline: 1.6208x; 1.4323x over previous
//
#include <hip/hip_runtime.h>

// PathDecoder: B=256, L=192, H=320, E=128, V=27000, T=8
constexpr int Bn = 256;
constexpr int Ln = 192;
constexpr int Hn = 320;
constexpr int En = 128;
constexpr int Vn = 27000;
constexpr int Tn = 8;
constexpr float NEGV   = -1e9f;
constexpr float LN_EPS = 1e-5f;

typedef __attribute__((ext_vector_type(8))) short bf16x8;
typedef __attribute__((ext_vector_type(4))) float f32x4;
typedef unsigned long long u64;
typedef unsigned int u32;
typedef unsigned short u16;

__device__ __forceinline__ float sigmoidf_(float x) { return 1.f / (1.f + expf(-x)); }
__device__ __forceinline__ u16 f2bf(float x) {
  unsigned u = __float_as_uint(x);
  return (u16)((u + 0x7fffu + ((u >> 16) & 1u)) >> 16);
}
__device__ __forceinline__ float bf2f(u16 h) { return __uint_as_float((unsigned)h << 16); }
__device__ __forceinline__ unsigned mono(float f) {
  unsigned u = __float_as_uint(f);
  return (u & 0x80000000u) ? ~u : (u | 0x80000000u);
}
__device__ __forceinline__ u64 shfl_xor_u64(u64 x, int off) {
  unsigned lo = (unsigned)x, hi = (unsigned)(x >> 32);
  lo = __shfl_xor(lo, off, 64);
  hi = __shfl_xor(hi, off, 64);
  return ((u64)hi << 32) | lo;
}

// ---------------------------------------------------------------------------
// split fp32 -> bf16 hi/lo (grid-stride)
__global__ __launch_bounds__(256) void k_split(const float* __restrict__ w,
                                               u16* __restrict__ hi,
                                               u16* __restrict__ lo, int n4) {
  for (int i = blockIdx.x * 256 + threadIdx.x; i < n4; i += gridDim.x * 256) {
    float4 v = ((const float4*)w)[i];
    u16 h0 = f2bf(v.x), h1 = f2bf(v.y), h2 = f2bf(v.z), h3 = f2bf(v.w);
    ((ushort4*)hi)[i] = make_ushort4(h0, h1, h2, h3);
    ((ushort4*)lo)[i] = make_ushort4(f2bf(v.x - bf2f(h0)), f2bf(v.y - bf2f(h1)),
                                     f2bf(v.z - bf2f(h2)), f2bf(v.w - bf2f(h3)));
  }
}

// wcat split + awT/cwT transposes + bias
__global__ __launch_bounds__(256) void k_prep2(
    const float* __restrict__ w_ih, const float* __restrict__ w_hh,
    const float* __restrict__ b_ih, const float* __restrict__ b_hh,
    const float* __restrict__ attn_w, const float* __restrict__ concat_w,
    u16* __restrict__ wch, u16* __restrict__ wcl,
    float* __restrict__ awT, float* __restrict__ cwT, float* __restrict__ biasc) {
  const int gid = blockIdx.x * 256 + threadIdx.x;
  const int NT = gridDim.x * 256;
  for (int i = gid; i < 4 * Hn * 112; i += NT) {   // [1280][448] split
    int r = i / 112, k = (i % 112) * 4;
    const float* src = (k < En) ? (w_ih + (size_t)r * En + k)
                                : (w_hh + (size_t)r * Hn + (k - En));
    float4 v = *(const float4*)src;
    size_t o = (size_t)r * 448 + k;
    u16 h0 = f2bf(v.x), h1 = f2bf(v.y), h2 = f2bf(v.z), h3 = f2bf(v.w);
    *(ushort4*)(wch + o) = make_ushort4(h0, h1, h2, h3);
    *(ushort4*)(wcl + o) = make_ushort4(f2bf(v.x - bf2f(h0)), f2bf(v.y - bf2f(h1)),
                                        f2bf(v.z - bf2f(h2)), f2bf(v.w - bf2f(h3)));
  }
  for (int i = gid; i < Hn * Hn; i += NT) {        // awT[k][j] = attn_w[j][k]
    int k = i / Hn, j = i % Hn;
    awT[i] = attn_w[(size_t)j * Hn + k];
  }
  for (int i = gid; i < 2 * Hn * Hn; i += NT) {    // cwT[k][j] = concat_w[j][k]
    int k = i / Hn, j = i % Hn;
    cwT[i] = concat_w[(size_t)j * (2 * Hn) + k];
  }
  for (int i = gid; i < 4 * Hn; i += NT) biasc[i] = b_ih[i] + b_hh[i];
}

// h0 = c0 = mean over valid length; zero amax
__global__ __launch_bounds__(320) void k_init(const float* __restrict__ enc,
                                              const int* __restrict__ lens,
                                              float* __restrict__ h32, float* __restrict__ c32,
                                              u16* __restrict__ hh, u16* __restrict__ hl,
                                              u64* __restrict__ amax) {
  int b = blockIdx.x, t = threadIdx.x;
  const float* p = enc + (size_t)b * Ln * Hn + t;
  float s = 0.f;
#pragma unroll 8
  for (int l = 0; l < Ln; ++l) s += p[(size_t)l * Hn];
  float hv = s / (float)lens[b];
  size_t o = (size_t)b * Hn + t;
  h32[o] = hv; c32[o] = hv;
  u16 hb = f2bf(hv);
  hh[o] = hb; hl[o] = f2bf(hv - bf2f(hb));
  if (b < Tn && t < Bn) amax[(size_t)b * Bn + t] = 0ull;
}

// ---------------------------------------------------------------------------
// gates GEMM (split-bf16 MFMA) + LSTM cell. grid 20 (j-blocks) x 512 (8 waves).
// wave tile: 32 b-rows x (4 gates x 16 h-cols), K=448.
__global__ __launch_bounds__(512) void k_gates(
    const u16* __restrict__ ebh, const u16* __restrict__ ebl,
    const u64* __restrict__ amax_prev, int t,
    const u16* __restrict__ wch, const u16* __restrict__ wcl,
    const float* __restrict__ biasc,
    const u16* __restrict__ hh_in, const u16* __restrict__ hl_in,
    const float* __restrict__ c_in, float* __restrict__ c_out,
    float* __restrict__ h32, u16* __restrict__ hh_out, u16* __restrict__ hl_out) {
  int tid = threadIdx.x, wv = tid >> 6, lane = tid & 63;
  int j0 = blockIdx.x * 16;
  int b0 = wv * 32;
  int lr = lane & 15, hi4 = lane >> 4, kg = hi4 * 8;
  int tkr[2];
#pragma unroll
  for (int mt = 0; mt < 2; ++mt) {
    int r = b0 + mt * 16 + lr;
    tkr[mt] = (t == 0) ? 1 : (int)(~(unsigned)amax_prev[r]);
  }
  f32x4 acc[2][4];
#pragma unroll
  for (int i = 0; i < 2; ++i)
#pragma unroll
    for (int j = 0; j < 4; ++j) acc[i][j] = (f32x4){0.f, 0.f, 0.f, 0.f};
  for (int k0 = 0; k0 < 448; k0 += 32) {
    bf16x8 af[2][2], bw[4][2];
#pragma unroll
    for (int mt = 0; mt < 2; ++mt) {
      int r = b0 + mt * 16 + lr;
      if (k0 < En) {
        size_t o = (size_t)tkr[mt] * En + k0 + kg;
        af[mt][0] = *(const bf16x8*)(ebh + o);
        af[mt][1] = *(const bf16x8*)(ebl + o);
      } else {
        size_t o = (size_t)r * Hn + (k0 - En) + kg;
        af[mt][0] = *(const bf16x8*)(hh_in + o);
        af[mt][1] = *(const bf16x8*)(hl_in + o);
      }
    }
#pragma unroll
    for (int g = 0; g < 4; ++g) {
      size_t o = (size_t)(g * Hn + j0 + lr) * 448 + k0 + kg;
      bw[g][0] = *(const bf16x8*)(wch + o);
      bw[g][1] = *(const bf16x8*)(wcl + o);
    }
#pragma unroll
    for (int mt = 0; mt < 2; ++mt)
#pragma unroll
      for (int g = 0; g < 4; ++g) {
        acc[mt][g] = __builtin_amdgcn_mfma_f32_16x16x32_bf16(af[mt][0], bw[g][0], acc[mt][g], 0, 0, 0);
        acc[mt][g] = __builtin_amdgcn_mfma_f32_16x16x32_bf16(af[mt][0], bw[g][1], acc[mt][g], 0, 0, 0);
        acc[mt][g] = __builtin_amdgcn_mfma_f32_16x16x32_bf16(af[mt][1], bw[g][0], acc[mt][g], 0, 0, 0);
      }
  }
  int jc = j0 + lr;
#pragma unroll
  for (int mt = 0; mt < 2; ++mt)
#pragma unroll
    for (int j = 0; j < 4; ++j) {
      int b = b0 + mt * 16 + hi4 * 4 + j;
      float iv = acc[mt][0][j] + biasc[jc];
      float fv = acc[mt][1][j] + biasc[Hn + jc];
      float gv = acc[mt][2][j] + biasc[2 * Hn + jc];
      float ov = acc[mt][3][j] + biasc[3 * Hn + jc];
      float co = c_in[(size_t)b * Hn + jc];
      float cn = sigmoidf_(fv) * co + sigmoidf_(iv) * tanhf(gv);
      float hn = sigmoidf_(ov) * tanhf(cn);
      size_t o = (size_t)b * Hn + jc;
      c_out[o] = cn;
      h32[o] = hn;
      u16 hb = f2bf(hn);
      hh_out[o] = hb;
      hl_out[o] = f2bf(hn - bf2f(hb));
    }
}

// ---------------------------------------------------------------------------
// attention (wave-split matvecs + online softmax single enc pass) + cat + LN.
// one block per batch row; 512 threads (8 waves).
__global__ __launch_bounds__(512) void k_attn(
    const float* __restrict__ enc, const int* __restrict__ lens,
    const float* __restrict__ awT, const float* __restrict__ cwT,
    const float* __restrict__ gamma, const float* __restrict__ beta,
    const float* __restrict__ h32, u16* __restrict__ th, u16* __restrict__ tl) {
  __shared__ float eL[64 * Hn];     // 80 KB enc chunk
  __shared__ float xs[2 * Hn];      // [h | ctx]
  __shared__ float ahs[Hn];
  __shared__ float part[8][Hn];     // 10 KB wave partials
  __shared__ float sc[64];
  __shared__ float rmS, rsS, rfS, rmu, rvar;

  int b = blockIdx.x, tid = threadIdx.x, wv = tid >> 6, lane = tid & 63;
  if (tid < Hn) xs[tid] = h32[(size_t)b * Hn + tid];
  if (tid == 0) { rmS = -3.402823466e38f; rsS = 0.f; }
  __syncthreads();

  // ah = attn_w @ h : wave-split over k (40 k's per wave)
  {
    float a[5] = {0.f, 0.f, 0.f, 0.f, 0.f};
    int kbeg = wv * 40;
    for (int k = kbeg; k < kbeg + 40; ++k) {
      float hk = xs[k];
      const float* row = awT + (size_t)k * Hn;
#pragma unroll
      for (int q = 0; q < 5; ++q) a[q] = fmaf(row[lane + 64 * q], hk, a[q]);
    }
#pragma unroll
    for (int q = 0; q < 5; ++q) part[wv][lane + 64 * q] = a[q];
  }
  __syncthreads();
  if (tid < Hn) {
    float s = 0.f;
#pragma unroll
    for (int w = 0; w < 8; ++w) s += part[w][tid];
    ahs[tid] = s;
  }
  __syncthreads();

  // online-softmax attention, single enc pass (3 chunks of 64 rows)
  int len = lens[b];
  float ctxacc = 0.f;
  const float* encB = enc + (size_t)b * Ln * Hn;
  for (int c = 0; c < 3; ++c) {
    const float4* src = (const float4*)(encB + (size_t)c * 64 * Hn);
#pragma unroll
    for (int i = 0; i < 10; ++i) ((float4*)eL)[tid + i * 512] = src[tid + i * 512];
    __syncthreads();
#pragma unroll
    for (int r = 0; r < 8; ++r) {
      int l = wv * 8 + r;
      float s = 0.f;
#pragma unroll
      for (int c5 = 0; c5 < 5; ++c5)
        s += eL[l * Hn + lane + 64 * c5] * ahs[lane + 64 * c5];
#pragma unroll
      for (int off = 32; off > 0; off >>= 1) s += __shfl_xor(s, off, 64);
      if (lane == 0) sc[l] = s + ((c * 64 + l < len) ? 0.f : NEGV);
    }
    __syncthreads();
    if (wv == 0) {
      float v = sc[lane];
      float m = v;
#pragma unroll
      for (int off = 32; off > 0; off >>= 1) m = fmaxf(m, __shfl_xor(m, off, 64));
      float oldm = rmS;
      float newm = fmaxf(oldm, m);
      float p = expf(v - newm);
      sc[lane] = p;
      float s = p;
#pragma unroll
      for (int off = 32; off > 0; off >>= 1) s += __shfl_xor(s, off, 64);
      if (lane == 0) {
        rfS = expf(oldm - newm);
        rsS = rsS * rfS + s;
        rmS = newm;
      }
    }
    __syncthreads();
    if (tid < Hn) {
      float f = rfS;
      float a = 0.f;
#pragma unroll 8
      for (int l = 0; l < 64; ++l) a += sc[l] * eL[l * Hn + tid];
      ctxacc = ctxacc * f + a;
    }
    __syncthreads();
  }
  if (tid < Hn) xs[Hn + tid] = ctxacc / rsS;
  __syncthreads();

  // cat = [h|ctx] @ concat_w^T : wave-split over 640 k (80 per wave)
  {
    float a[5] = {0.f, 0.f, 0.f, 0.f, 0.f};
    int kbeg = wv * 80;
    for (int k = kbeg; k < kbeg + 80; ++k) {
      float xk = xs[k];
      const float* row = cwT + (size_t)k * Hn;
#pragma unroll
      for (int q = 0; q < 5; ++q) a[q] = fmaf(row[lane + 64 * q], xk, a[q]);
    }
#pragma unroll
    for (int q = 0; q < 5; ++q) part[wv][lane + 64 * q] = a[q];
  }
  __syncthreads();
  float catv = 0.f;
  if (tid < Hn) {
    float s = 0.f;
#pragma unroll
    for (int w = 0; w < 8; ++w) s += part[w][tid];
    catv = s;
    ahs[tid] = s;
  }
  __syncthreads();
  if (tid < 64) {
    float s1 = 0.f, s2 = 0.f;
    for (int i = tid; i < Hn; i += 64) { float v = ahs[i]; s1 += v; s2 += v * v; }
#pragma unroll
    for (int off = 32; off > 0; off >>= 1) {
      s1 += __shfl_xor(s1, off, 64);
      s2 += __shfl_xor(s2, off, 64);
    }
    if (tid == 0) {
      float mu = s1 * (1.f / 320.f);
      rmu = mu;
      rvar = s2 * (1.f / 320.f) - mu * mu;
    }
  }
  __syncthreads();
  if (tid < Hn) {
    float rstd = 1.f / sqrtf(rvar + LN_EPS);
    float y = (catv - rmu) * rstd * gamma[tid] + beta[tid];
    float tv = tanhf(y);
    u16 tb = f2bf(tv);
    size_t o = (size_t)b * Hn + tid;
    th[o] = tb;
    tl[o] = f2bf(tv - bf2f(tb));
  }
}

// ---------------------------------------------------------------------------
// projection (split-bf16 MFMA) + fused argmax. grid (106, 4), block 256.
// Bijective XCD swizzle: consecutive v-panels stay on one XCD's L2.
__global__ __launch_bounds__(256) void k_proj(
    const u16* __restrict__ th, const u16* __restrict__ tl,
    const u16* __restrict__ pwh, const u16* __restrict__ pwl,
    float* __restrict__ ot, u64* __restrict__ amax_t) {
  __shared__ u64 red[4][64];
  int tid = threadIdx.x, wave = tid >> 6, lane = tid & 63;
  int x = blockIdx.x;                 // 0..105
  int xcd = x & 7, s = x >> 3;
  int vblk = (xcd < 2) ? (xcd * 14 + s) : (28 + (xcd - 2) * 13 + s);
  int v0 = vblk * 256 + wave * 64;
  int b0 = blockIdx.y * 64;
  int lr = lane & 15, hi4 = lane >> 4, kg = hi4 * 8;

  f32x4 acc[4][4];
#pragma unroll
  for (int i = 0; i < 4; ++i)
#pragma unroll
    for (int j = 0; j < 4; ++j) acc[i][j] = (f32x4){0.f, 0.f, 0.f, 0.f};
  const bf16x8 zf = {0, 0, 0, 0, 0, 0, 0, 0};

  for (int k0 = 0; k0 < Hn; k0 += 32) {
    bf16x8 af[4][2], bw[4][2];
#pragma unroll
    for (int mt = 0; mt < 4; ++mt) {
      size_t o = (size_t)(b0 + mt * 16 + lr) * Hn + k0 + kg;
      af[mt][0] = *(const bf16x8*)(th + o);
      af[mt][1] = *(const bf16x8*)(tl + o);
    }
#pragma unroll
    for (int nt = 0; nt < 4; ++nt) {
      int v = v0 + nt * 16 + lr;
      if (v < Vn) {
        size_t o = (size_t)v * Hn + k0 + kg;
        bw[nt][0] = *(const bf16x8*)(pwh + o);
        bw[nt][1] = *(const bf16x8*)(pwl + o);
      } else {
        bw[nt][0] = zf; bw[nt][1] = zf;
      }
    }
#pragma unroll
    for (int mt = 0; mt < 4; ++mt)
#pragma unroll
      for (int nt = 0; nt < 4; ++nt) {
        acc[mt][nt] = __builtin_amdgcn_mfma_f32_16x16x32_bf16(af[mt][0], bw[nt][0], acc[mt][nt], 0, 0, 0);
        acc[mt][nt] = __builtin_amdgcn_mfma_f32_16x16x32_bf16(af[mt][0], bw[nt][1], acc[mt][nt], 0, 0, 0);
        acc[mt][nt] = __builtin_amdgcn_mfma_f32_16x16x32_bf16(af[mt][1], bw[nt][0], acc[mt][nt], 0, 0, 0);
      }
  }

  int orow = hi4 * 4;
#pragma unroll
  for (int mt = 0; mt < 4; ++mt)
#pragma unroll
    for (int nt = 0; nt < 4; ++nt) {
      int v = v0 + nt * 16 + lr;
      if (v < Vn) {
#pragma unroll
        for (int j = 0; j < 4; ++j)
          __builtin_nontemporal_store(acc[mt][nt][j],
              &ot[(size_t)(b0 + mt * 16 + orow + j) * Vn + v]);
      }
    }

  // fused argmax: key = (mono(val)<<32) | ~idx ; max key == first max
  u64 best[4][4];
#pragma unroll
  for (int mt = 0; mt < 4; ++mt)
#pragma unroll
    for (int j = 0; j < 4; ++j) {
      u64 k = 0ull;
#pragma unroll
      for (int nt = 0; nt < 4; ++nt) {
        int v = v0 + nt * 16 + lr;
        if (v < Vn) {
          u64 kk = ((u64)mono(acc[mt][nt][j]) << 32) | (u64)(unsigned)(~v);
          if (kk > k) k = kk;
        }
      }
      best[mt][j] = k;
    }
#pragma unroll
  for (int off = 1; off < 16; off <<= 1)
#pragma unroll
    for (int mt = 0; mt < 4; ++mt)
#pragma unroll
      for (int j = 0; j < 4; ++j) {
        u64 o = shfl_xor_u64(best[mt][j], off);
        if (o > best[mt][j]) best[mt][j] = o;
      }
  if (lr == 0) {
#pragma unroll
    for (int mt = 0; mt < 4; ++mt)
#pragma unroll
      for (int j = 0; j < 4; ++j) red[wave][mt * 16 + orow + j] = best[mt][j];
  }
  __syncthreads();
  if (tid < 64) {
    u64 k = red[0][tid];
#pragma unroll
    for (int w = 1; w < 4; ++w)
      if (red[w][tid] > k) k = red[w][tid];
    atomicMax(&amax_t[b0 + tid], k);
  }
}

// ---------------------------------------------------------------------------
extern "C" void kernel_launch(void* const* d_in, const int* in_sizes, int n_in,
                              void* d_out, int out_size, void* d_ws, size_t ws_size,
                              hipStream_t stream) {
  const float* enc      = (const float*)d_in[0];
  const int*   lens     = (const int*)d_in[1];
  const float* emb      = (const float*)d_in[2];
  const float* w_ih     = (const float*)d_in[3];
  const float* w_hh     = (const float*)d_in[4];
  const float* b_ih     = (const float*)d_in[5];
  const float* b_hh     = (const float*)d_in[6];
  const float* attn_w   = (const float*)d_in[7];
  const float* concat_w = (const float*)d_in[8];
  const float* gamma    = (const float*)d_in[9];
  const float* beta     = (const float*)d_in[10];
  const float* proj_w   = (const float*)d_in[11];
  float* out = (float*)d_out;

  char* p = (char*)d_ws;
  auto alloc = [&](size_t bytes, size_t align) -> char* {
    uintptr_t a = ((uintptr_t)p + align - 1) & ~(uintptr_t)(align - 1);
    char* r = (char*)a;
    p = r + bytes;
    return r;
  };
  const size_t HB = (size_t)Bn * Hn;
  u64* amax  = (u64*)alloc((size_t)Tn * Bn * 8, 8);
  float* h32 = (float*)alloc(HB * 4, 16);
  float* c32 = (float*)alloc(2 * HB * 4, 16);
  float* awT = (float*)alloc((size_t)Hn * Hn * 4, 16);
  float* cwT = (float*)alloc((size_t)2 * Hn * Hn * 4, 16);
  float* biasc = (float*)alloc((size_t)4 * Hn * 4, 16);
  u16* hh  = (u16*)alloc(2 * HB * 2, 16);
  u16* hl  = (u16*)alloc(2 * HB * 2, 16);
  u16* th  = (u16*)alloc(HB * 2, 16);
  u16* tl  = (u16*)alloc(HB * 2, 16);
  u16* wch = (u16*)alloc((size_t)4 * Hn * 448 * 2, 16);
  u16* wcl = (u16*)alloc((size_t)4 * Hn * 448 * 2, 16);
  u16* ebh = (u16*)alloc((size_t)Vn * En * 2, 16);
  u16* ebl = (u16*)alloc((size_t)Vn * En * 2, 16);
  u16* pwh = (u16*)alloc((size_t)Vn * Hn * 2, 16);
  u16* pwl = (u16*)alloc((size_t)Vn * Hn * 2, 16);

  k_split<<<2048, 256, 0, stream>>>(proj_w, pwh, pwl, Vn * Hn / 4);
  k_split<<<512, 256, 0, stream>>>(emb, ebh, ebl, Vn * En / 4);
  k_prep2<<<256, 256, 0, stream>>>(w_ih, w_hh, b_ih, b_hh, attn_w, concat_w,
                                   wch, wcl, awT, cwT, biasc);
  k_init<<<Bn, Hn, 0, stream>>>(enc, lens, h32, c32, hh, hl, amax);

  for (int t = 0; t < Tn; ++t) {
    int hin = t & 1, hout = hin ^ 1;
    const u64* aprev = amax + (size_t)((t == 0) ? 0 : (t - 1)) * Bn;
    k_gates<<<20, 512, 0, stream>>>(ebh, ebl, aprev, t, wch, wcl, biasc,
                                    hh + hin * HB, hl + hin * HB,
                                    c32 + hin * HB, c32 + hout * HB,
                                    h32, hh + hout * HB, hl + hout * HB);
    k_attn<<<Bn, 512, 0, stream>>>(enc, lens, awT, cwT, gamma, beta, h32, th, tl);
    k_proj<<<dim3(106, 4), 256, 0, stream>>>(th, tl, pwh, pwl,
                                             out + (size_t)t * Bn * Vn,
                                             amax + (size_t)t * Bn);
  }
}

// Round 13
// 831.520 us; speedup vs baseline: 2.0163x; 1.2440x over previous
//
#include <hip/hip_runtime.h>

// PathDecoder: B=256, L=192, H=320, E=128, V=27000, T=8
constexpr int Bn = 256;
constexpr int Ln = 192;
constexpr int Hn = 320;
constexpr int En = 128;
constexpr int Vn = 27000;
constexpr int Tn = 8;
constexpr float NEGV   = -1e9f;
constexpr float LN_EPS = 1e-5f;

typedef __attribute__((ext_vector_type(8))) short bf16x8;
typedef __attribute__((ext_vector_type(4))) float f32x4;
typedef unsigned long long u64;
typedef unsigned short u16;

__device__ __forceinline__ float sigmoidf_(float x) { return 1.f / (1.f + expf(-x)); }
__device__ __forceinline__ u16 f2bf(float x) {
  unsigned u = __float_as_uint(x);
  return (u16)((u + 0x7fffu + ((u >> 16) & 1u)) >> 16);
}
__device__ __forceinline__ float bf2f(u16 h) { return __uint_as_float((unsigned)h << 16); }
__device__ __forceinline__ unsigned mono(float f) {
  unsigned u = __float_as_uint(f);
  return (u & 0x80000000u) ? ~u : (u | 0x80000000u);
}
__device__ __forceinline__ u64 shfl_xor_u64(u64 x, int off) {
  unsigned lo = (unsigned)x, hi = (unsigned)(x >> 32);
  lo = __shfl_xor(lo, off, 64);
  hi = __shfl_xor(hi, off, 64);
  return ((u64)hi << 32) | lo;
}

// ---------------------------------------------------------------------------
// ONE prep kernel: all weight splits/transposes + bias + h0/c0 + amax zero.
// grid 1280 x 320 (5 waves).
__global__ __launch_bounds__(320) void k_prep(
    const float* __restrict__ enc, const int* __restrict__ lens,
    const float* __restrict__ emb, const float* __restrict__ proj_w,
    const float* __restrict__ w_ih, const float* __restrict__ w_hh,
    const float* __restrict__ b_ih, const float* __restrict__ b_hh,
    const float* __restrict__ attn_w, const float* __restrict__ concat_w,
    u16* __restrict__ pwh, u16* __restrict__ pwl,
    u16* __restrict__ ebh, u16* __restrict__ ebl,
    u16* __restrict__ wch, u16* __restrict__ wcl,
    float* __restrict__ awT, float* __restrict__ cwT, float* __restrict__ biasc,
    float* __restrict__ h32, float* __restrict__ c32,
    u16* __restrict__ hh, u16* __restrict__ hl, u64* __restrict__ amax) {
  const int gid = blockIdx.x * 320 + threadIdx.x;
  const int NT = gridDim.x * 320;

  // h0 = c0 = mean over valid length (first 256 blocks, one row each)
  if (blockIdx.x < Bn) {
    int b = blockIdx.x, t = threadIdx.x;
    const float* p = enc + (size_t)b * Ln * Hn + t;
    float s = 0.f;
#pragma unroll 8
    for (int l = 0; l < Ln; ++l) s += p[(size_t)l * Hn];
    float hv = s / (float)lens[b];
    size_t o = (size_t)b * Hn + t;
    h32[o] = hv; c32[o] = hv;
    u16 hb = f2bf(hv);
    hh[o] = hb; hl[o] = f2bf(hv - bf2f(hb));
  }

  for (int i = gid; i < Vn * Hn / 4; i += NT) {
    float4 v = ((const float4*)proj_w)[i];
    u16 h0 = f2bf(v.x), h1 = f2bf(v.y), h2 = f2bf(v.z), h3 = f2bf(v.w);
    ((ushort4*)pwh)[i] = make_ushort4(h0, h1, h2, h3);
    ((ushort4*)pwl)[i] = make_ushort4(f2bf(v.x - bf2f(h0)), f2bf(v.y - bf2f(h1)),
                                      f2bf(v.z - bf2f(h2)), f2bf(v.w - bf2f(h3)));
  }
  for (int i = gid; i < Vn * En / 4; i += NT) {
    float4 v = ((const float4*)emb)[i];
    u16 h0 = f2bf(v.x), h1 = f2bf(v.y), h2 = f2bf(v.z), h3 = f2bf(v.w);
    ((ushort4*)ebh)[i] = make_ushort4(h0, h1, h2, h3);
    ((ushort4*)ebl)[i] = make_ushort4(f2bf(v.x - bf2f(h0)), f2bf(v.y - bf2f(h1)),
                                      f2bf(v.z - bf2f(h2)), f2bf(v.w - bf2f(h3)));
  }
  for (int i = gid; i < 4 * Hn * 112; i += NT) {   // w_cat [1280][448] split
    int r = i / 112, k = (i % 112) * 4;
    const float* src = (k < En) ? (w_ih + (size_t)r * En + k)
                                : (w_hh + (size_t)r * Hn + (k - En));
    float4 v = *(const float4*)src;
    size_t o = (size_t)r * 448 + k;
    u16 h0 = f2bf(v.x), h1 = f2bf(v.y), h2 = f2bf(v.z), h3 = f2bf(v.w);
    *(ushort4*)(wch + o) = make_ushort4(h0, h1, h2, h3);
    *(ushort4*)(wcl + o) = make_ushort4(f2bf(v.x - bf2f(h0)), f2bf(v.y - bf2f(h1)),
                                        f2bf(v.z - bf2f(h2)), f2bf(v.w - bf2f(h3)));
  }
  for (int i = gid; i < Hn * Hn; i += NT) {        // awT[k][j] = attn_w[j][k]
    int k = i / Hn, j = i % Hn;
    awT[i] = attn_w[(size_t)j * Hn + k];
  }
  for (int i = gid; i < 2 * Hn * Hn; i += NT) {    // cwT[k][j] = concat_w[j][k]
    int k = i / Hn, j = i % Hn;
    cwT[i] = concat_w[(size_t)j * (2 * Hn) + k];
  }
  for (int i = gid; i < 4 * Hn; i += NT) biasc[i] = b_ih[i] + b_hh[i];
  for (int i = gid; i < Tn * Bn; i += NT) amax[i] = 0ull;
}

// ---------------------------------------------------------------------------
// gates GEMM (split-bf16 MFMA) + LSTM cell.
// grid 80 = (20 j-blocks) x (4 b-quarters); block 256 (4 waves).
// wave tile: 16 b-rows x (4 gates x 16 h-cols), K=448.
__global__ __launch_bounds__(256) void k_gates(
    const u16* __restrict__ ebh, const u16* __restrict__ ebl,
    const u64* __restrict__ amax_prev, int t,
    const u16* __restrict__ wch, const u16* __restrict__ wcl,
    const float* __restrict__ biasc,
    const u16* __restrict__ hh_in, const u16* __restrict__ hl_in,
    const float* __restrict__ c_in, float* __restrict__ c_out,
    float* __restrict__ h32, u16* __restrict__ hh_out, u16* __restrict__ hl_out) {
  int tid = threadIdx.x, wv = tid >> 6, lane = tid & 63;
  int j0 = (blockIdx.x >> 2) * 16;
  int b0 = (blockIdx.x & 3) * 64 + wv * 16;
  int lr = lane & 15, hi4 = lane >> 4, kg = hi4 * 8;
  int r = b0 + lr;
  int tkr = (t == 0) ? 1 : (int)(~(unsigned)amax_prev[r]);

  f32x4 acc[4];
#pragma unroll
  for (int j = 0; j < 4; ++j) acc[j] = (f32x4){0.f, 0.f, 0.f, 0.f};
  for (int k0 = 0; k0 < 448; k0 += 32) {
    bf16x8 af[2], bw[4][2];
    if (k0 < En) {
      size_t o = (size_t)tkr * En + k0 + kg;
      af[0] = *(const bf16x8*)(ebh + o);
      af[1] = *(const bf16x8*)(ebl + o);
    } else {
      size_t o = (size_t)r * Hn + (k0 - En) + kg;
      af[0] = *(const bf16x8*)(hh_in + o);
      af[1] = *(const bf16x8*)(hl_in + o);
    }
#pragma unroll
    for (int g = 0; g < 4; ++g) {
      size_t o = (size_t)(g * Hn + j0 + lr) * 448 + k0 + kg;
      bw[g][0] = *(const bf16x8*)(wch + o);
      bw[g][1] = *(const bf16x8*)(wcl + o);
    }
#pragma unroll
    for (int g = 0; g < 4; ++g) {
      acc[g] = __builtin_amdgcn_mfma_f32_16x16x32_bf16(af[0], bw[g][0], acc[g], 0, 0, 0);
      acc[g] = __builtin_amdgcn_mfma_f32_16x16x32_bf16(af[0], bw[g][1], acc[g], 0, 0, 0);
      acc[g] = __builtin_amdgcn_mfma_f32_16x16x32_bf16(af[1], bw[g][0], acc[g], 0, 0, 0);
    }
  }
  int jc = j0 + lr;
#pragma unroll
  for (int j = 0; j < 4; ++j) {
    int b = b0 + hi4 * 4 + j;
    float iv = acc[0][j] + biasc[jc];
    float fv = acc[1][j] + biasc[Hn + jc];
    float gv = acc[2][j] + biasc[2 * Hn + jc];
    float ov = acc[3][j] + biasc[3 * Hn + jc];
    float co = c_in[(size_t)b * Hn + jc];
    float cn = sigmoidf_(fv) * co + sigmoidf_(iv) * tanhf(gv);
    float hn = sigmoidf_(ov) * tanhf(cn);
    size_t o = (size_t)b * Hn + jc;
    c_out[o] = cn;
    h32[o] = hn;
    u16 hb = f2bf(hn);
    hh_out[o] = hb;
    hl_out[o] = f2bf(hn - bf2f(hb));
  }
}

// ---------------------------------------------------------------------------
// attention (wave-split matvecs + online softmax single enc pass) + cat + LN.
// one block per batch row; 512 threads (8 waves).
__global__ __launch_bounds__(512) void k_attn(
    const float* __restrict__ enc, const int* __restrict__ lens,
    const float* __restrict__ awT, const float* __restrict__ cwT,
    const float* __restrict__ gamma, const float* __restrict__ beta,
    const float* __restrict__ h32, u16* __restrict__ th, u16* __restrict__ tl) {
  __shared__ float eL[64 * Hn];     // 80 KB enc chunk
  __shared__ float xs[2 * Hn];      // [h | ctx]
  __shared__ float ahs[Hn];
  __shared__ float part[8][Hn];
  __shared__ float sc[64];
  __shared__ float rmS, rsS, rfS, rmu, rvar;

  int b = blockIdx.x, tid = threadIdx.x, wv = tid >> 6, lane = tid & 63;
  if (tid < Hn) xs[tid] = h32[(size_t)b * Hn + tid];
  if (tid == 0) { rmS = -3.402823466e38f; rsS = 0.f; }
  __syncthreads();

  // ah = attn_w @ h : wave-split over k
  {
    float a[5] = {0.f, 0.f, 0.f, 0.f, 0.f};
    int kbeg = wv * 40;
    for (int k = kbeg; k < kbeg + 40; ++k) {
      float hk = xs[k];
      const float* row = awT + (size_t)k * Hn;
#pragma unroll
      for (int q = 0; q < 5; ++q) a[q] = fmaf(row[lane + 64 * q], hk, a[q]);
    }
#pragma unroll
    for (int q = 0; q < 5; ++q) part[wv][lane + 64 * q] = a[q];
  }
  __syncthreads();
  if (tid < Hn) {
    float s = 0.f;
#pragma unroll
    for (int w = 0; w < 8; ++w) s += part[w][tid];
    ahs[tid] = s;
  }
  __syncthreads();

  // online-softmax attention, single enc pass (3 chunks of 64 rows)
  int len = lens[b];
  float ctxacc = 0.f;
  const float* encB = enc + (size_t)b * Ln * Hn;
  for (int c = 0; c < 3; ++c) {
    const float4* src = (const float4*)(encB + (size_t)c * 64 * Hn);
#pragma unroll
    for (int i = 0; i < 10; ++i) ((float4*)eL)[tid + i * 512] = src[tid + i * 512];
    __syncthreads();
#pragma unroll
    for (int r = 0; r < 8; ++r) {
      int l = wv * 8 + r;
      float s = 0.f;
#pragma unroll
      for (int c5 = 0; c5 < 5; ++c5)
        s += eL[l * Hn + lane + 64 * c5] * ahs[lane + 64 * c5];
#pragma unroll
      for (int off = 32; off > 0; off >>= 1) s += __shfl_xor(s, off, 64);
      if (lane == 0) sc[l] = s + ((c * 64 + l < len) ? 0.f : NEGV);
    }
    __syncthreads();
    if (wv == 0) {
      float v = sc[lane];
      float m = v;
#pragma unroll
      for (int off = 32; off > 0; off >>= 1) m = fmaxf(m, __shfl_xor(m, off, 64));
      float oldm = rmS;
      float newm = fmaxf(oldm, m);
      float p = expf(v - newm);
      sc[lane] = p;
      float s = p;
#pragma unroll
      for (int off = 32; off > 0; off >>= 1) s += __shfl_xor(s, off, 64);
      if (lane == 0) {
        rfS = expf(oldm - newm);
        rsS = rsS * rfS + s;
        rmS = newm;
      }
    }
    __syncthreads();
    if (tid < Hn) {
      float f = rfS;
      float a = 0.f;
#pragma unroll 8
      for (int l = 0; l < 64; ++l) a += sc[l] * eL[l * Hn + tid];
      ctxacc = ctxacc * f + a;
    }
    __syncthreads();
  }
  if (tid < Hn) xs[Hn + tid] = ctxacc / rsS;
  __syncthreads();

  // cat = [h|ctx] @ concat_w^T : wave-split over 640 k
  {
    float a[5] = {0.f, 0.f, 0.f, 0.f, 0.f};
    int kbeg = wv * 80;
    for (int k = kbeg; k < kbeg + 80; ++k) {
      float xk = xs[k];
      const float* row = cwT + (size_t)k * Hn;
#pragma unroll
      for (int q = 0; q < 5; ++q) a[q] = fmaf(row[lane + 64 * q], xk, a[q]);
    }
#pragma unroll
    for (int q = 0; q < 5; ++q) part[wv][lane + 64 * q] = a[q];
  }
  __syncthreads();
  float catv = 0.f;
  if (tid < Hn) {
    float s = 0.f;
#pragma unroll
    for (int w = 0; w < 8; ++w) s += part[w][tid];
    catv = s;
    ahs[tid] = s;
  }
  __syncthreads();
  if (tid < 64) {
    float s1 = 0.f, s2 = 0.f;
    for (int i = tid; i < Hn; i += 64) { float v = ahs[i]; s1 += v; s2 += v * v; }
#pragma unroll
    for (int off = 32; off > 0; off >>= 1) {
      s1 += __shfl_xor(s1, off, 64);
      s2 += __shfl_xor(s2, off, 64);
    }
    if (tid == 0) {
      float mu = s1 * (1.f / 320.f);
      rmu = mu;
      rvar = s2 * (1.f / 320.f) - mu * mu;
    }
  }
  __syncthreads();
  if (tid < Hn) {
    float rstd = 1.f / sqrtf(rvar + LN_EPS);
    float y = (catv - rmu) * rstd * gamma[tid] + beta[tid];
    float tv = tanhf(y);
    u16 tb = f2bf(tv);
    size_t o = (size_t)b * Hn + tid;
    th[o] = tb;
    tl[o] = f2bf(tv - bf2f(tb));
  }
}

// ---------------------------------------------------------------------------
// projection (split-bf16 MFMA) + fused argmax. grid 424 (= 8 XCD x 53 pairs).
// Pair-swizzle: pair g = (vblk<<2)|y assigned vblk-major per XCD, so one XCD
// owns all 4 b-panels of each v-panel consecutively (B stays in its L2).
__global__ __launch_bounds__(256) void k_proj(
    const u16* __restrict__ th, const u16* __restrict__ tl,
    const u16* __restrict__ pwh, const u16* __restrict__ pwl,
    float* __restrict__ ot, u64* __restrict__ amax_t) {
  __shared__ u64 red[4][64];
  int tid = threadIdx.x, wave = tid >> 6, lane = tid & 63;
  int bid = blockIdx.x;               // 0..423
  int xcd = bid & 7, s = bid >> 3;    // s 0..52
  int g = xcd * 53 + s;               // bijective 0..423
  int vblk = g >> 2, y = g & 3;
  int v0 = vblk * 256 + wave * 64;
  int b0 = y * 64;
  int lr = lane & 15, hi4 = lane >> 4, kg = hi4 * 8;

  f32x4 acc[4][4];
#pragma unroll
  for (int i = 0; i < 4; ++i)
#pragma unroll
    for (int j = 0; j < 4; ++j) acc[i][j] = (f32x4){0.f, 0.f, 0.f, 0.f};
  const bf16x8 zf = {0, 0, 0, 0, 0, 0, 0, 0};

  for (int k0 = 0; k0 < Hn; k0 += 32) {
    bf16x8 af[4][2], bw[4][2];
#pragma unroll
    for (int mt = 0; mt < 4; ++mt) {
      size_t o = (size_t)(b0 + mt * 16 + lr) * Hn + k0 + kg;
      af[mt][0] = *(const bf16x8*)(th + o);
      af[mt][1] = *(const bf16x8*)(tl + o);
    }
#pragma unroll
    for (int nt = 0; nt < 4; ++nt) {
      int v = v0 + nt * 16 + lr;
      if (v < Vn) {
        size_t o = (size_t)v * Hn + k0 + kg;
        bw[nt][0] = *(const bf16x8*)(pwh + o);
        bw[nt][1] = *(const bf16x8*)(pwl + o);
      } else {
        bw[nt][0] = zf; bw[nt][1] = zf;
      }
    }
#pragma unroll
    for (int mt = 0; mt < 4; ++mt)
#pragma unroll
      for (int nt = 0; nt < 4; ++nt) {
        acc[mt][nt] = __builtin_amdgcn_mfma_f32_16x16x32_bf16(af[mt][0], bw[nt][0], acc[mt][nt], 0, 0, 0);
        acc[mt][nt] = __builtin_amdgcn_mfma_f32_16x16x32_bf16(af[mt][0], bw[nt][1], acc[mt][nt], 0, 0, 0);
        acc[mt][nt] = __builtin_amdgcn_mfma_f32_16x16x32_bf16(af[mt][1], bw[nt][0], acc[mt][nt], 0, 0, 0);
      }
  }

  int orow = hi4 * 4;
#pragma unroll
  for (int mt = 0; mt < 4; ++mt)
#pragma unroll
    for (int nt = 0; nt < 4; ++nt) {
      int v = v0 + nt * 16 + lr;
      if (v < Vn) {
#pragma unroll
        for (int j = 0; j < 4; ++j)
          __builtin_nontemporal_store(acc[mt][nt][j],
              &ot[(size_t)(b0 + mt * 16 + orow + j) * Vn + v]);
      }
    }

  // fused argmax: key = (mono(val)<<32) | ~idx ; max key == first max
  u64 best[4][4];
#pragma unroll
  for (int mt = 0; mt < 4; ++mt)
#pragma unroll
    for (int j = 0; j < 4; ++j) {
      u64 k = 0ull;
#pragma unroll
      for (int nt = 0; nt < 4; ++nt) {
        int v = v0 + nt * 16 + lr;
        if (v < Vn) {
          u64 kk = ((u64)mono(acc[mt][nt][j]) << 32) | (u64)(unsigned)(~v);
          if (kk > k) k = kk;
        }
      }
      best[mt][j] = k;
    }
#pragma unroll
  for (int off = 1; off < 16; off <<= 1)
#pragma unroll
    for (int mt = 0; mt < 4; ++mt)
#pragma unroll
      for (int j = 0; j < 4; ++j) {
        u64 o = shfl_xor_u64(best[mt][j], off);
        if (o > best[mt][j]) best[mt][j] = o;
      }
  if (lr == 0) {
#pragma unroll
    for (int mt = 0; mt < 4; ++mt)
#pragma unroll
      for (int j = 0; j < 4; ++j) red[wave][mt * 16 + orow + j] = best[mt][j];
  }
  __syncthreads();
  if (tid < 64) {
    u64 k = red[0][tid];
#pragma unroll
    for (int w = 1; w < 4; ++w)
      if (red[w][tid] > k) k = red[w][tid];
    atomicMax(&amax_t[b0 + tid], k);
  }
}

// ---------------------------------------------------------------------------
extern "C" void kernel_launch(void* const* d_in, const int* in_sizes, int n_in,
                              void* d_out, int out_size, void* d_ws, size_t ws_size,
                              hipStream_t stream) {
  const float* enc      = (const float*)d_in[0];
  const int*   lens     = (const int*)d_in[1];
  const float* emb      = (const float*)d_in[2];
  const float* w_ih     = (const float*)d_in[3];
  const float* w_hh     = (const float*)d_in[4];
  const float* b_ih     = (const float*)d_in[5];
  const float* b_hh     = (const float*)d_in[6];
  const float* attn_w   = (const float*)d_in[7];
  const float* concat_w = (const float*)d_in[8];
  const float* gamma    = (const float*)d_in[9];
  const float* beta     = (const float*)d_in[10];
  const float* proj_w   = (const float*)d_in[11];
  float* out = (float*)d_out;

  char* p = (char*)d_ws;
  auto alloc = [&](size_t bytes, size_t align) -> char* {
    uintptr_t a = ((uintptr_t)p + align - 1) & ~(uintptr_t)(align - 1);
    char* r = (char*)a;
    p = r + bytes;
    return r;
  };
  const size_t HB = (size_t)Bn * Hn;
  u64* amax  = (u64*)alloc((size_t)Tn * Bn * 8, 8);
  float* h32 = (float*)alloc(HB * 4, 16);
  float* c32 = (float*)alloc(2 * HB * 4, 16);
  float* awT = (float*)alloc((size_t)Hn * Hn * 4, 16);
  float* cwT = (float*)alloc((size_t)2 * Hn * Hn * 4, 16);
  float* biasc = (float*)alloc((size_t)4 * Hn * 4, 16);
  u16* hh  = (u16*)alloc(2 * HB * 2, 16);
  u16* hl  = (u16*)alloc(2 * HB * 2, 16);
  u16* th  = (u16*)alloc(HB * 2, 16);
  u16* tl  = (u16*)alloc(HB * 2, 16);
  u16* wch = (u16*)alloc((size_t)4 * Hn * 448 * 2, 16);
  u16* wcl = (u16*)alloc((size_t)4 * Hn * 448 * 2, 16);
  u16* ebh = (u16*)alloc((size_t)Vn * En * 2, 16);
  u16* ebl = (u16*)alloc((size_t)Vn * En * 2, 16);
  u16* pwh = (u16*)alloc((size_t)Vn * Hn * 2, 16);
  u16* pwl = (u16*)alloc((size_t)Vn * Hn * 2, 16);

  k_prep<<<1280, 320, 0, stream>>>(enc, lens, emb, proj_w, w_ih, w_hh, b_ih, b_hh,
                                   attn_w, concat_w, pwh, pwl, ebh, ebl, wch, wcl,
                                   awT, cwT, biasc, h32, c32, hh, hl, amax);

  for (int t = 0; t < Tn; ++t) {
    int hin = t & 1, hout = hin ^ 1;
    const u64* aprev = amax + (size_t)((t == 0) ? 0 : (t - 1)) * Bn;
    k_gates<<<80, 256, 0, stream>>>(ebh, ebl, aprev, t, wch, wcl, biasc,
                                    hh + hin * HB, hl + hin * HB,
                                    c32 + hin * HB, c32 + hout * HB,
                                    h32, hh + hout * HB, hl + hout * HB);
    k_attn<<<Bn, 512, 0, stream>>>(enc, lens, awT, cwT, gamma, beta, h32, th, tl);
    k_proj<<<424, 256, 0, stream>>>(th, tl, pwh, pwl,
                                    out + (size_t)t * Bn * Vn,
                                    amax + (size_t)t * Bn);
  }
}

// Round 16
// 804.063 us; speedup vs baseline: 2.0851x; 1.0341x over previous
//
#include <hip/hip_runtime.h>

// PathDecoder: B=256, L=192, H=320, E=128, V=27000, T=8
constexpr int Bn = 256;
constexpr int Ln = 192;
constexpr int Hn = 320;
constexpr int En = 128;
constexpr int Vn = 27000;
constexpr int Tn = 8;
constexpr float NEGV   = -1e9f;
constexpr float LN_EPS = 1e-5f;

typedef __attribute__((ext_vector_type(8))) short bf16x8;
typedef __attribute__((ext_vector_type(4))) float f32x4;
typedef unsigned long long u64;
typedef unsigned short u16;

__device__ __forceinline__ float sigmoidf_(float x) { return 1.f / (1.f + expf(-x)); }
__device__ __forceinline__ u16 f2bf(float x) {
  unsigned u = __float_as_uint(x);
  return (u16)((u + 0x7fffu + ((u >> 16) & 1u)) >> 16);
}
__device__ __forceinline__ float bf2f(u16 h) { return __uint_as_float((unsigned)h << 16); }
__device__ __forceinline__ unsigned mono(float f) {
  unsigned u = __float_as_uint(f);
  return (u & 0x80000000u) ? ~u : (u | 0x80000000u);
}
__device__ __forceinline__ u64 shfl_xor_u64(u64 x, int off) {
  unsigned lo = (unsigned)x, hi = (unsigned)(x >> 32);
  lo = __shfl_xor(lo, off, 64);
  hi = __shfl_xor(hi, off, 64);
  return ((u64)hi << 32) | lo;
}

// ---------------------------------------------------------------------------
// ONE prep kernel: weight splits/transposes + bias + h0/c0 + amax zero.
// grid 1280 x 320 (5 waves).
__global__ __launch_bounds__(320) void k_prep(
    const float* __restrict__ enc, const int* __restrict__ lens,
    const float* __restrict__ emb, const float* __restrict__ proj_w,
    const float* __restrict__ w_ih, const float* __restrict__ w_hh,
    const float* __restrict__ b_ih, const float* __restrict__ b_hh,
    const float* __restrict__ attn_w, const float* __restrict__ concat_w,
    u16* __restrict__ pwh, u16* __restrict__ pwl,
    u16* __restrict__ ebh, u16* __restrict__ ebl,
    u16* __restrict__ wch, u16* __restrict__ wcl,
    float* __restrict__ awT, float* __restrict__ cwT, float* __restrict__ biasc,
    float* __restrict__ h32, float* __restrict__ c32,
    u16* __restrict__ hh, u16* __restrict__ hl, u64* __restrict__ amax) {
  const int gid = blockIdx.x * 320 + threadIdx.x;
  const int NT = gridDim.x * 320;

  // h0 = c0 = mean over valid length (first 256 blocks, one row each)
  if (blockIdx.x < Bn) {
    int b = blockIdx.x, t = threadIdx.x;
    const float* p = enc + (size_t)b * Ln * Hn + t;
    float s = 0.f;
#pragma unroll 8
    for (int l = 0; l < Ln; ++l) s += p[(size_t)l * Hn];
    float hv = s / (float)lens[b];
    size_t o = (size_t)b * Hn + t;
    h32[o] = hv; c32[o] = hv;
    u16 hb = f2bf(hv);
    hh[o] = hb; hl[o] = f2bf(hv - bf2f(hb));
  }

  for (int i = gid; i < Vn * Hn / 4; i += NT) {
    float4 v = ((const float4*)proj_w)[i];
    u16 h0 = f2bf(v.x), h1 = f2bf(v.y), h2 = f2bf(v.z), h3 = f2bf(v.w);
    ((ushort4*)pwh)[i] = make_ushort4(h0, h1, h2, h3);
    ((ushort4*)pwl)[i] = make_ushort4(f2bf(v.x - bf2f(h0)), f2bf(v.y - bf2f(h1)),
                                      f2bf(v.z - bf2f(h2)), f2bf(v.w - bf2f(h3)));
  }
  for (int i = gid; i < Vn * En / 4; i += NT) {
    float4 v = ((const float4*)emb)[i];
    u16 h0 = f2bf(v.x), h1 = f2bf(v.y), h2 = f2bf(v.z), h3 = f2bf(v.w);
    ((ushort4*)ebh)[i] = make_ushort4(h0, h1, h2, h3);
    ((ushort4*)ebl)[i] = make_ushort4(f2bf(v.x - bf2f(h0)), f2bf(v.y - bf2f(h1)),
                                      f2bf(v.z - bf2f(h2)), f2bf(v.w - bf2f(h3)));
  }
  for (int i = gid; i < 4 * Hn * 112; i += NT) {   // w_cat [1280][448] split
    int r = i / 112, k = (i % 112) * 4;
    const float* src = (k < En) ? (w_ih + (size_t)r * En + k)
                                : (w_hh + (size_t)r * Hn + (k - En));
    float4 v = *(const float4*)src;
    size_t o = (size_t)r * 448 + k;
    u16 h0 = f2bf(v.x), h1 = f2bf(v.y), h2 = f2bf(v.z), h3 = f2bf(v.w);
    *(ushort4*)(wch + o) = make_ushort4(h0, h1, h2, h3);
    *(ushort4*)(wcl + o) = make_ushort4(f2bf(v.x - bf2f(h0)), f2bf(v.y - bf2f(h1)),
                                        f2bf(v.z - bf2f(h2)), f2bf(v.w - bf2f(h3)));
  }
  for (int i = gid; i < Hn * Hn; i += NT) {        // awT[k][j] = attn_w[j][k]
    int k = i / Hn, j = i % Hn;
    awT[i] = attn_w[(size_t)j * Hn + k];
  }
  for (int i = gid; i < 2 * Hn * Hn; i += NT) {    // cwT[k][j] = concat_w[j][k]
    int k = i / Hn, j = i % Hn;
    cwT[i] = concat_w[(size_t)j * (2 * Hn) + k];
  }
  for (int i = gid; i < 4 * Hn; i += NT) biasc[i] = b_ih[i] + b_hh[i];
  for (int i = gid; i < Tn * Bn; i += NT) amax[i] = 0ull;
}

// ---------------------------------------------------------------------------
// gates GEMM (split-bf16 MFMA) + LSTM cell.
// grid 80 = (20 j-blocks) x (4 b-quarters); block 256 (4 waves).
__global__ __launch_bounds__(256) void k_gates(
    const u16* __restrict__ ebh, const u16* __restrict__ ebl,
    const u64* __restrict__ amax_prev, int t,
    const u16* __restrict__ wch, const u16* __restrict__ wcl,
    const float* __restrict__ biasc,
    const u16* __restrict__ hh_in, const u16* __restrict__ hl_in,
    const float* __restrict__ c_in, float* __restrict__ c_out,
    float* __restrict__ h32, u16* __restrict__ hh_out, u16* __restrict__ hl_out) {
  int tid = threadIdx.x, wv = tid >> 6, lane = tid & 63;
  int j0 = (blockIdx.x >> 2) * 16;
  int b0 = (blockIdx.x & 3) * 64 + wv * 16;
  int lr = lane & 15, hi4 = lane >> 4, kg = hi4 * 8;
  int r = b0 + lr;
  int tkr = (t == 0) ? 1 : (int)(~(unsigned)amax_prev[r]);

  f32x4 acc[4];
#pragma unroll
  for (int j = 0; j < 4; ++j) acc[j] = (f32x4){0.f, 0.f, 0.f, 0.f};
  for (int k0 = 0; k0 < 448; k0 += 32) {
    bf16x8 af[2], bw[4][2];
    if (k0 < En) {
      size_t o = (size_t)tkr * En + k0 + kg;
      af[0] = *(const bf16x8*)(ebh + o);
      af[1] = *(const bf16x8*)(ebl + o);
    } else {
      size_t o = (size_t)r * Hn + (k0 - En) + kg;
      af[0] = *(const bf16x8*)(hh_in + o);
      af[1] = *(const bf16x8*)(hl_in + o);
    }
#pragma unroll
    for (int g = 0; g < 4; ++g) {
      size_t o = (size_t)(g * Hn + j0 + lr) * 448 + k0 + kg;
      bw[g][0] = *(const bf16x8*)(wch + o);
      bw[g][1] = *(const bf16x8*)(wcl + o);
    }
#pragma unroll
    for (int g = 0; g < 4; ++g) {
      acc[g] = __builtin_amdgcn_mfma_f32_16x16x32_bf16(af[0], bw[g][0], acc[g], 0, 0, 0);
      acc[g] = __builtin_amdgcn_mfma_f32_16x16x32_bf16(af[0], bw[g][1], acc[g], 0, 0, 0);
      acc[g] = __builtin_amdgcn_mfma_f32_16x16x32_bf16(af[1], bw[g][0], acc[g], 0, 0, 0);
    }
  }
  int jc = j0 + lr;
#pragma unroll
  for (int j = 0; j < 4; ++j) {
    int b = b0 + hi4 * 4 + j;
    float iv = acc[0][j] + biasc[jc];
    float fv = acc[1][j] + biasc[Hn + jc];
    float gv = acc[2][j] + biasc[2 * Hn + jc];
    float ov = acc[3][j] + biasc[3 * Hn + jc];
    float co = c_in[(size_t)b * Hn + jc];
    float cn = sigmoidf_(fv) * co + sigmoidf_(iv) * tanhf(gv);
    float hn = sigmoidf_(ov) * tanhf(cn);
    size_t o = (size_t)b * Hn + jc;
    c_out[o] = cn;
    h32[o] = hn;
    u16 hb = f2bf(hn);
    hh_out[o] = hb;
    hl_out[o] = f2bf(hn - bf2f(hb));
  }
}

// ---------------------------------------------------------------------------
// attention (wave-split matvecs + online softmax, fp32 enc) + cat + LN.
// one block per batch row; 512 threads (8 waves).
__global__ __launch_bounds__(512) void k_attn(
    const float* __restrict__ enc, const int* __restrict__ lens,
    const float* __restrict__ awT, const float* __restrict__ cwT,
    const float* __restrict__ gamma, const float* __restrict__ beta,
    const float* __restrict__ h32, u16* __restrict__ th, u16* __restrict__ tl) {
  __shared__ float eL[64 * Hn];     // 80 KB enc chunk
  __shared__ float xs[2 * Hn];      // [h | ctx]
  __shared__ float ahs[Hn];
  __shared__ float part[8][Hn];
  __shared__ float sc[64];
  __shared__ float rmS, rsS, rfS, rmu, rvar;

  int b = blockIdx.x, tid = threadIdx.x, wv = tid >> 6, lane = tid & 63;
  if (tid < Hn) xs[tid] = h32[(size_t)b * Hn + tid];
  if (tid == 0) { rmS = -3.402823466e38f; rsS = 0.f; }
  __syncthreads();

  // ah = attn_w @ h : wave-split over k
  {
    float a[5] = {0.f, 0.f, 0.f, 0.f, 0.f};
    int kbeg = wv * 40;
    for (int k = kbeg; k < kbeg + 40; ++k) {
      float hk = xs[k];
      const float* row = awT + (size_t)k * Hn;
#pragma unroll
      for (int q = 0; q < 5; ++q) a[q] = fmaf(row[lane + 64 * q], hk, a[q]);
    }
#pragma unroll
    for (int q = 0; q < 5; ++q) part[wv][lane + 64 * q] = a[q];
  }
  __syncthreads();
  if (tid < Hn) {
    float s = 0.f;
#pragma unroll
    for (int w = 0; w < 8; ++w) s += part[w][tid];
    ahs[tid] = s;
  }
  __syncthreads();

  // online-softmax attention, single enc pass (3 chunks of 64 rows)
  int len = lens[b];
  float ctxacc = 0.f;
  const float* encB = enc + (size_t)b * Ln * Hn;
  for (int c = 0; c < 3; ++c) {
    const float4* src = (const float4*)(encB + (size_t)c * 64 * Hn);
#pragma unroll
    for (int i = 0; i < 10; ++i) ((float4*)eL)[tid + i * 512] = src[tid + i * 512];
    __syncthreads();
#pragma unroll
    for (int r = 0; r < 8; ++r) {
      int l = wv * 8 + r;
      float s = 0.f;
#pragma unroll
      for (int c5 = 0; c5 < 5; ++c5)
        s += eL[l * Hn + lane + 64 * c5] * ahs[lane + 64 * c5];
#pragma unroll
      for (int off = 32; off > 0; off >>= 1) s += __shfl_xor(s, off, 64);
      if (lane == 0) sc[l] = s + ((c * 64 + l < len) ? 0.f : NEGV);
    }
    __syncthreads();
    if (wv == 0) {
      float v = sc[lane];
      float m = v;
#pragma unroll
      for (int off = 32; off > 0; off >>= 1) m = fmaxf(m, __shfl_xor(m, off, 64));
      float oldm = rmS;
      float newm = fmaxf(oldm, m);
      float p = expf(v - newm);
      sc[lane] = p;
      float s = p;
#pragma unroll
      for (int off = 32; off > 0; off >>= 1) s += __shfl_xor(s, off, 64);
      if (lane == 0) {
        rfS = expf(oldm - newm);
        rsS = rsS * rfS + s;
        rmS = newm;
      }
    }
    __syncthreads();
    if (tid < Hn) {
      float f = rfS;
      float a = 0.f;
#pragma unroll 8
      for (int l = 0; l < 64; ++l) a += sc[l] * eL[l * Hn + tid];
      ctxacc = ctxacc * f + a;
    }
    __syncthreads();
  }
  if (tid < Hn) xs[Hn + tid] = ctxacc / rsS;
  __syncthreads();

  // cat = [h|ctx] @ concat_w^T : wave-split over 640 k
  {
    float a[5] = {0.f, 0.f, 0.f, 0.f, 0.f};
    int kbeg = wv * 80;
    for (int k = kbeg; k < kbeg + 80; ++k) {
      float xk = xs[k];
      const float* row = cwT + (size_t)k * Hn;
#pragma unroll
      for (int q = 0; q < 5; ++q) a[q] = fmaf(row[lane + 64 * q], xk, a[q]);
    }
#pragma unroll
    for (int q = 0; q < 5; ++q) part[wv][lane + 64 * q] = a[q];
  }
  __syncthreads();
  float catv = 0.f;
  if (tid < Hn) {
    float s = 0.f;
#pragma unroll
    for (int w = 0; w < 8; ++w) s += part[w][tid];
    catv = s;
    ahs[tid] = s;
  }
  __syncthreads();
  if (tid < 64) {
    float s1 = 0.f, s2 = 0.f;
    for (int i = tid; i < Hn; i += 64) { float v = ahs[i]; s1 += v; s2 += v * v; }
#pragma unroll
    for (int off = 32; off > 0; off >>= 1) {
      s1 += __shfl_xor(s1, off, 64);
      s2 += __shfl_xor(s2, off, 64);
    }
    if (tid == 0) {
      float mu = s1 * (1.f / 320.f);
      rmu = mu;
      rvar = s2 * (1.f / 320.f) - mu * mu;
    }
  }
  __syncthreads();
  if (tid < Hn) {
    float rstd = 1.f / sqrtf(rvar + LN_EPS);
    float y = (catv - rmu) * rstd * gamma[tid] + beta[tid];
    float tv = tanhf(y);
    u16 tb = f2bf(tv);
    size_t o = (size_t)b * Hn + tid;
    th[o] = tb;
    tl[o] = f2bf(tv - bf2f(tb));
  }
}

// ---------------------------------------------------------------------------
// projection (split-bf16 MFMA) + fused argmax + LDS-coalesced logits write.
// grid 424 (= 8 XCD x 53 pairs), block 256 (4 waves).
__global__ __launch_bounds__(256) void k_proj(
    const u16* __restrict__ th, const u16* __restrict__ tl,
    const u16* __restrict__ pwh, const u16* __restrict__ pwl,
    float* __restrict__ ot, u64* __restrict__ amax_t) {
  __shared__ u64 red[4][64];
  __shared__ float sL[64][260];      // 64 rows x 256 cols, stride 260 (16B-aligned)
  int tid = threadIdx.x, wave = tid >> 6, lane = tid & 63;
  int bid = blockIdx.x;               // 0..423
  int xcd = bid & 7, s = bid >> 3;    // s 0..52
  int g = xcd * 53 + s;               // bijective 0..423
  int vblk = g >> 2, y = g & 3;
  int v0 = vblk * 256 + wave * 64;
  int b0 = y * 64;
  int lr = lane & 15, hi4 = lane >> 4, kg = hi4 * 8;

  f32x4 acc[4][4];
#pragma unroll
  for (int i = 0; i < 4; ++i)
#pragma unroll
    for (int j = 0; j < 4; ++j) acc[i][j] = (f32x4){0.f, 0.f, 0.f, 0.f};
  const bf16x8 zf = {0, 0, 0, 0, 0, 0, 0, 0};

  for (int k0 = 0; k0 < Hn; k0 += 32) {
    bf16x8 af[4][2], bw[4][2];
#pragma unroll
    for (int mt = 0; mt < 4; ++mt) {
      size_t o = (size_t)(b0 + mt * 16 + lr) * Hn + k0 + kg;
      af[mt][0] = *(const bf16x8*)(th + o);
      af[mt][1] = *(const bf16x8*)(tl + o);
    }
#pragma unroll
    for (int nt = 0; nt < 4; ++nt) {
      int v = v0 + nt * 16 + lr;
      if (v < Vn) {
        size_t o = (size_t)v * Hn + k0 + kg;
        bw[nt][0] = *(const bf16x8*)(pwh + o);
        bw[nt][1] = *(const bf16x8*)(pwl + o);
      } else {
        bw[nt][0] = zf; bw[nt][1] = zf;
      }
    }
#pragma unroll
    for (int mt = 0; mt < 4; ++mt)
#pragma unroll
      for (int nt = 0; nt < 4; ++nt) {
        acc[mt][nt] = __builtin_amdgcn_mfma_f32_16x16x32_bf16(af[mt][0], bw[nt][0], acc[mt][nt], 0, 0, 0);
        acc[mt][nt] = __builtin_amdgcn_mfma_f32_16x16x32_bf16(af[mt][0], bw[nt][1], acc[mt][nt], 0, 0, 0);
        acc[mt][nt] = __builtin_amdgcn_mfma_f32_16x16x32_bf16(af[mt][1], bw[nt][0], acc[mt][nt], 0, 0, 0);
      }
  }

  int orow = hi4 * 4;
  // stage accumulators into LDS tile [row][col]
#pragma unroll
  for (int mt = 0; mt < 4; ++mt)
#pragma unroll
    for (int nt = 0; nt < 4; ++nt)
#pragma unroll
      for (int j = 0; j < 4; ++j)
        sL[mt * 16 + orow + j][wave * 64 + nt * 16 + lr] = acc[mt][nt][j];

  // fused argmax: key = (mono(val)<<32) | ~idx ; max key == first max
  u64 best[4][4];
#pragma unroll
  for (int mt = 0; mt < 4; ++mt)
#pragma unroll
    for (int j = 0; j < 4; ++j) {
      u64 k = 0ull;
#pragma unroll
      for (int nt = 0; nt < 4; ++nt) {
        int v = v0 + nt * 16 + lr;
        if (v < Vn) {
          u64 kk = ((u64)mono(acc[mt][nt][j]) << 32) | (u64)(unsigned)(~v);
          if (kk > k) k = kk;
        }
      }
      best[mt][j] = k;
    }
#pragma unroll
  for (int off = 1; off < 16; off <<= 1)
#pragma unroll
    for (int mt = 0; mt < 4; ++mt)
#pragma unroll
      for (int j = 0; j < 4; ++j) {
        u64 o = shfl_xor_u64(best[mt][j], off);
        if (o > best[mt][j]) best[mt][j] = o;
      }
  if (lr == 0) {
#pragma unroll
    for (int mt = 0; mt < 4; ++mt)
#pragma unroll
      for (int j = 0; j < 4; ++j) red[wave][mt * 16 + orow + j] = best[mt][j];
  }
  __syncthreads();
  if (tid < 64) {
    u64 k = red[0][tid];
#pragma unroll
    for (int w = 1; w < 4; ++w)
      if (red[w][tid] > k) k = red[w][tid];
    atomicMax(&amax_t[b0 + tid], k);
  }

  // coalesced logits write: each row is 1 KB contiguous (64 threads x f32x4)
  int rem = Vn - vblk * 256;               // valid cols this v-panel (<=256)
  int colq = tid & 63, r0 = tid >> 6;
  if (colq * 4 < rem) {
#pragma unroll
    for (int r = r0; r < 64; r += 4) {
      f32x4 vv = *(const f32x4*)&sL[r][colq * 4];
      __builtin_nontemporal_store(vv,
          (f32x4*)(ot + (size_t)(b0 + r) * Vn + vblk * 256 + colq * 4));
    }
  }
}

// ---------------------------------------------------------------------------
extern "C" void kernel_launch(void* const* d_in, const int* in_sizes, int n_in,
                              void* d_out, int out_size, void* d_ws, size_t ws_size,
                              hipStream_t stream) {
  const float* enc      = (const float*)d_in[0];
  const int*   lens     = (const int*)d_in[1];
  const float* emb      = (const float*)d_in[2];
  const float* w_ih     = (const float*)d_in[3];
  const float* w_hh     = (const float*)d_in[4];
  const float* b_ih     = (const float*)d_in[5];
  const float* b_hh     = (const float*)d_in[6];
  const float* attn_w   = (const float*)d_in[7];
  const float* concat_w = (const float*)d_in[8];
  const float* gamma    = (const float*)d_in[9];
  const float* beta     = (const float*)d_in[10];
  const float* proj_w   = (const float*)d_in[11];
  float* out = (float*)d_out;

  char* p = (char*)d_ws;
  auto alloc = [&](size_t bytes, size_t align) -> char* {
    uintptr_t a = ((uintptr_t)p + align - 1) & ~(uintptr_t)(align - 1);
    char* r = (char*)a;
    p = r + bytes;
    return r;
  };
  const size_t HB = (size_t)Bn * Hn;
  u64* amax  = (u64*)alloc((size_t)Tn * Bn * 8, 8);
  float* h32 = (float*)alloc(HB * 4, 16);
  float* c32 = (float*)alloc(2 * HB * 4, 16);
  float* awT = (float*)alloc((size_t)Hn * Hn * 4, 16);
  float* cwT = (float*)alloc((size_t)2 * Hn * Hn * 4, 16);
  float* biasc = (float*)alloc((size_t)4 * Hn * 4, 16);
  u16* hh  = (u16*)alloc(2 * HB * 2, 16);
  u16* hl  = (u16*)alloc(2 * HB * 2, 16);
  u16* th  = (u16*)alloc(HB * 2, 16);
  u16* tl  = (u16*)alloc(HB * 2, 16);
  u16* wch = (u16*)alloc((size_t)4 * Hn * 448 * 2, 16);
  u16* wcl = (u16*)alloc((size_t)4 * Hn * 448 * 2, 16);
  u16* ebh = (u16*)alloc((size_t)Vn * En * 2, 16);
  u16* ebl = (u16*)alloc((size_t)Vn * En * 2, 16);
  u16* pwh = (u16*)alloc((size_t)Vn * Hn * 2, 16);
  u16* pwl = (u16*)alloc((size_t)Vn * Hn * 2, 16);

  k_prep<<<1280, 320, 0, stream>>>(enc, lens, emb, proj_w, w_ih, w_hh, b_ih, b_hh,
                                   attn_w, concat_w, pwh, pwl, ebh, ebl, wch, wcl,
                                   awT, cwT, biasc, h32, c32, hh, hl, amax);

  for (int t = 0; t < Tn; ++t) {
    int hin = t & 1, hout = hin ^ 1;
    const u64* aprev = amax + (size_t)((t == 0) ? 0 : (t - 1)) * Bn;
    k_gates<<<80, 256, 0, stream>>>(ebh, ebl, aprev, t, wch, wcl, biasc,
                                    hh + hin * HB, hl + hin * HB,
                                    c32 + hin * HB, c32 + hout * HB,
                                    h32, hh + hout * HB, hl + hout * HB);
    k_attn<<<Bn, 512, 0, stream>>>(enc, lens, awT, cwT, gamma, beta, h32, th, tl);
    k_proj<<<424, 256, 0, stream>>>(th, tl, pwh, pwl,
                                    out + (size_t)t * Bn * Vn,
                                    amax + (size_t)t * Bn);
  }
}